// Round 13
// baseline (569.637 us; speedup 1.0000x reference)
//
#include <hip/hip_runtime.h>
#include <hip/hip_bf16.h>

#define B_   8
#define S_   1024
#define D_   512
#define H_   8
#define DK_  64
#define DFF_ 2048

typedef __hip_bfloat16 bf16;
typedef __attribute__((ext_vector_type(8))) short bf16x8;
typedef __attribute__((ext_vector_type(4))) float f32x4;

// flag==1 -> bf16 data; flag==0 -> fp32 data
__device__ __forceinline__ float ldmix(const void* p, size_t i, int f) {
    return f ? __bfloat162float(((const bf16*)p)[i]) : ((const float*)p)[i];
}
__device__ __forceinline__ void store_o(float* p, float v) { *p = v; }
__device__ __forceinline__ void store_o(bf16* p, float v)  { *p = __float2bfloat16(v); }

// async global->LDS, 16B per lane; lds base wave-uniform (lane*16 implicit)
__device__ __forceinline__ void gl_lds16(const void* g, void* l) {
    __builtin_amdgcn_global_load_lds(
        (const __attribute__((address_space(1))) unsigned int*)g,
        (__attribute__((address_space(3))) unsigned int*)l, 16, 0, 0);
}

#define WAITV(N)  asm volatile("s_waitcnt vmcnt(" #N ")" ::: "memory")

// ---------------- detect dtype + zero LN stats + constants ----------------
__global__ __launch_bounds__(64) void detect_k(const unsigned short* __restrict__ x,
                                               float* __restrict__ stats,
                                               int* __restrict__ flag)
{
    if (threadIdx.x < 48) stats[threadIdx.x] = 0.f;
    int cnt = 0;
    for (int i = threadIdx.x; i < 4096; i += 64) {
        int e = (x[i] >> 7) & 0xFF;
        if (e >= 0xC0) cnt++;
    }
#pragma unroll
    for (int off = 32; off; off >>= 1) cnt += __shfl_xor(cnt, off);
    if (threadIdx.x == 0) { flag[0] = (cnt > 16) ? 0 : 1; flag[1] = 1; }
}

// ---------------- masks -> additive float ----------------
__global__ __launch_bounds__(256) void maskf_k(const int* __restrict__ trg,
                                               const int* __restrict__ src,
                                               float* __restrict__ trgf,
                                               float* __restrict__ srcf)
{
    int i = blockIdx.x * 256 + threadIdx.x;
    if (i < 8192) trgf[i] = trg[i] ? 0.f : -1.0e10f;
    else          srcf[i - 8192] = src[i - 8192] ? 0.f : -1.0e10f;
}

// ---------------- x,y -> bf16 (8 elems/thread; pure copy when already bf16) ----------------
__global__ __launch_bounds__(256) void convxy_k(const void* __restrict__ x,
                                                const void* __restrict__ y,
                                                bf16* __restrict__ xb, bf16* __restrict__ yb,
                                                const int* __restrict__ flag)
{
    const int f = flag[0];
    const int N8 = 8192 * 512 / 8;   // 524288
    int i = blockIdx.x * 256 + threadIdx.x;
    const void* src; bf16* dst; size_t base;
    if (i < N8) { src = x; dst = xb; base = (size_t)i * 8; }
    else        { src = y; dst = yb; base = (size_t)(i - N8) * 8; }
    if (f) {
        *(uint4*)(dst + base) = *(const uint4*)((const bf16*)src + base);
    } else {
        const float4 a = *(const float4*)((const float*)src + base);
        const float4 b = *(const float4*)((const float*)src + base + 4);
        bf16 o[8] = {__float2bfloat16(a.x), __float2bfloat16(a.y),
                     __float2bfloat16(a.z), __float2bfloat16(a.w),
                     __float2bfloat16(b.x), __float2bfloat16(b.y),
                     __float2bfloat16(b.z), __float2bfloat16(b.w)};
        *(uint4*)(dst + base) = *(uint4*)o;
    }
}

// ---------------- 6 qkv weight repacks: in[h,d,k] -> out[(h*64+k), d] ----------------
__global__ __launch_bounds__(256) void repack6_k(const void* __restrict__ w0, const void* __restrict__ w1,
                                                 const void* __restrict__ w2, const void* __restrict__ w3,
                                                 const void* __restrict__ w4, const void* __restrict__ w5,
                                                 bf16* __restrict__ out, const int* __restrict__ flag)
{
    const int f = flag[0];
    const int widx = blockIdx.x >> 10;
    const int j = ((blockIdx.x & 1023) << 8) + threadIdx.x;
    const void* in = widx == 0 ? w0 : widx == 1 ? w1 : widx == 2 ? w2
                   : widx == 3 ? w3 : widx == 4 ? w4 : w5;
    int n = j >> 9, d = j & 511;
    int h = n >> 6, k = n & 63;
    out[(size_t)widx * 262144 + j] =
        __float2bfloat16(ldmix(in, (size_t)h * (D_ * DK_) + (size_t)d * DK_ + k, f));
}

// ---------------- 4 [N][K] weight converts (8 elems/thread) ----------------
__global__ __launch_bounds__(256) void convw4_k(const void* __restrict__ wo1, const void* __restrict__ wo2,
                                                const void* __restrict__ pw1, const void* __restrict__ pw2,
                                                bf16* __restrict__ out, const int* __restrict__ flag)
{
    const int f = flag[0];
    const size_t i8 = (size_t)(blockIdx.x * 256 + threadIdx.x) * 8;   // < 2621440
    const void* in; size_t off;
    if (i8 < 262144)       { in = wo1; off = 0; }
    else if (i8 < 524288)  { in = wo2; off = 262144; }
    else if (i8 < 1572864) { in = pw1; off = 524288; }
    else                   { in = pw2; off = 1572864; }
    const size_t s = i8 - off;
    if (f) {
        *(uint4*)(out + i8) = *(const uint4*)((const bf16*)in + s);
    } else {
        const float4 a = *(const float4*)((const float*)in + s);
        const float4 b = *(const float4*)((const float*)in + s + 4);
        bf16 o[8] = {__float2bfloat16(a.x), __float2bfloat16(a.y),
                     __float2bfloat16(a.z), __float2bfloat16(a.w),
                     __float2bfloat16(b.x), __float2bfloat16(b.y),
                     __float2bfloat16(b.z), __float2bfloat16(b.w)};
        *(uint4*)(out + i8) = *(uint4*)o;
    }
}

// ==================== MFMA GEMM core (BM=64, BN=64, BK=64) ====================
// 4 waves 2x2; wave tile 32x32, acc[2][2]; 8 MFMA + 8 ds_read_b128 per wave per iter.
// R12 post-mortem: 3 schedules (128-tile/PF2, 64sq BK32/PF2, 64sq BK64/PF2) all land
// 58-73us with all pipes ~9% busy -- the invariant is PF=2 (WAITV covers only 2
// iteration-times). THIS ROUND isolates prefetch depth: PF=3, NBUF=4 (64KB LDS,
// 2 blocks/CU). Single delta vs the R12 measurement.
//   - steady WAITV(8) (stages t+1,t+2 in flight), tail 8->4->0.
//   - stage issued AFTER the entry barrier: all waves passed barrier(t) => their
//     iter t-1 ds_reads retired (lgkm before MFMA), so writing buf (t+3)%4
//     (== buffer read at t-1) is WAR-safe with no trailing barrier.
//   - LDS swizzle 8 granules/row: g' = g ^ (row&7); wave64 ds_read_b128 spreads
//     evenly over all 32 banks (conflict-free at the 8-cycle floor; R8/R12
//     measured SQ_LDS_BANK_CONFLICT = 0). Inverse-swizzled global source,
//     linear LDS dest (both-sides rule).
__device__ __forceinline__ void gemm_core(const bf16* __restrict__ A, const bf16* __restrict__ Wt,
                                          int K, int m0, int n0, bf16* As, bf16* Bs,
                                          f32x4 (&acc)[2][2])
{
    const int tid = threadIdx.x;
    const int lane = tid & 63, w = tid >> 6;
    const int wr = w >> 1, wc = w & 1;
    const int l16 = lane & 15, quad = lane >> 4;
    const int r0 = tid >> 3;                       // 0..31: tile row this lane stages
    const int g0 = (tid & 7) ^ (r0 & 7);           // inverse-swizzled 16B granule (8/row)
    const bf16* pa = A  + (size_t)(m0 + r0) * K + g0 * 8;
    const bf16* pb = Wt + (size_t)(n0 + r0) * K + g0 * 8;
    const size_t rhalf = (size_t)32 * K;           // rows 32..63

    int aoff[2][2], boff[2][2];
#pragma unroll
    for (int i = 0; i < 2; ++i) {
        const int ra = wr * 32 + i * 16 + l16;
        const int rb = wc * 32 + i * 16 + l16;
#pragma unroll
        for (int ks = 0; ks < 2; ++ks) {
            aoff[i][ks] = ra * 64 + (((ks << 2) + quad) ^ (ra & 7)) * 8;
            boff[i][ks] = rb * 64 + (((ks << 2) + quad) ^ (rb & 7)) * 8;
        }
    }

    // 4 loads per wave per stage: A tile 8KB + B tile 8KB, 4 waves x 16B/lane
    auto stage = [&](int bi, int k0) {
        bf16* a = As + bi * 4096;
        bf16* b = Bs + bi * 4096;
        gl_lds16(pa + k0,         a + w * 512);
        gl_lds16(pa + k0 + rhalf, a + 2048 + w * 512);
        gl_lds16(pb + k0,         b + w * 512);
        gl_lds16(pb + k0 + rhalf, b + 2048 + w * 512);
    };

    const int NT = K >> 6;                          // min 8 (K=512)
    stage(0, 0);
    stage(1, 64);
    stage(2, 128);
    int cur = 0;

    for (int t = 0; t < NT; ++t) {
        // retire stage t's 4 loads; keep deeper prefetch in flight (never 0 mid-loop)
        if (t + 2 < NT) WAITV(8);
        else if (t + 1 < NT) WAITV(4);
        else WAITV(0);
        __builtin_amdgcn_s_barrier();               // all waves' buf-t writes landed
        __builtin_amdgcn_sched_barrier(0);
        if (t + 3 < NT) stage((t + 3) & 3, (t + 3) << 6);   // buf (t+3)%4

        const bf16* Ab = As + cur * 4096;
        const bf16* Bb = Bs + cur * 4096;
        bf16x8 af[2][2], bg[2][2];
#pragma unroll
        for (int i = 0; i < 2; ++i)
#pragma unroll
            for (int ks = 0; ks < 2; ++ks) {
                af[i][ks] = *(const bf16x8*)&Ab[aoff[i][ks]];
                bg[i][ks] = *(const bf16x8*)&Bb[boff[i][ks]];
            }
#pragma unroll
        for (int ks = 0; ks < 2; ++ks)
#pragma unroll
            for (int i = 0; i < 2; ++i)
#pragma unroll
                for (int j = 0; j < 2; ++j)
                    acc[i][j] = __builtin_amdgcn_mfma_f32_16x16x32_bf16(af[i][ks], bg[j][ks], acc[i][j], 0, 0, 0);

        cur = (cur + 1) & 3;
    }
}

// standard GEMM: C[M,N] = A @ Wt^T + bias (+relu) (+res) (+LN-stats)
// 1-D grid = 8 * 16 * Gx: xcd=lin&7 owns a 16-M-tile stripe, N fastest.
template <bool HAS_RES, bool RELU, bool STATS, typename OutT>
__global__ __launch_bounds__(256)
void mgemm_k(const bf16* __restrict__ A, const bf16* __restrict__ Wt,
             const void* __restrict__ bias, const void* __restrict__ res,
             OutT* __restrict__ C, int N, int K, int Gx,
             const int* __restrict__ bflag, const int* __restrict__ rflag,
             float* __restrict__ stats)
{
    __shared__ bf16 As[4 * 4096];
    __shared__ bf16 Bs[4 * 4096];
    const int lin = blockIdx.x;
    const int mt = (lin & 7) * 16 + (lin >> 3) / Gx;
    const int nt = (lin >> 3) % Gx;
    const int m0 = mt * 64, n0 = nt * 64;

    f32x4 acc[2][2];
#pragma unroll
    for (int i = 0; i < 2; ++i)
#pragma unroll
        for (int j = 0; j < 2; ++j) acc[i][j] = (f32x4){0.f, 0.f, 0.f, 0.f};

    gemm_core(A, Wt, K, m0, n0, As, Bs, acc);

    const int tid = threadIdx.x;
    const int lane = tid & 63, w = tid >> 6;
    const int wr = w >> 1, wc = w & 1;
    const int l16 = lane & 15, quad = lane >> 4;
    const int bf = bflag[0];
    int rf = 0;
    if constexpr (HAS_RES) rf = rflag[0];

    float s = 0.f, s2 = 0.f;
#pragma unroll
    for (int i = 0; i < 2; ++i) {
        const int row = m0 + wr * 32 + i * 16 + quad * 4;
#pragma unroll
        for (int j = 0; j < 2; ++j) {
            const int col = n0 + wc * 32 + j * 16 + l16;
            const float bv = ldmix(bias, col, bf);
#pragma unroll
            for (int r = 0; r < 4; ++r) {
                float c = acc[i][j][r] + bv;
                if constexpr (RELU) c = fmaxf(c, 0.f);
                if constexpr (HAS_RES) c += ldmix(res, (size_t)(row + r) * N + col, rf);
                if constexpr (STATS) { s += c; s2 += c * c; }
                store_o(&C[(size_t)(row + r) * N + col], c);
            }
        }
    }
    if constexpr (STATS) {
#pragma unroll
        for (int off = 32; off; off >>= 1) { s += __shfl_xor(s, off); s2 += __shfl_xor(s2, off); }
        __syncthreads();                     // all waves done with As
        float* red = (float*)As;
        if (lane == 0) { red[w * 2] = s; red[w * 2 + 1] = s2; }
        __syncthreads();
        if (tid == 0) {
            const int b = m0 >> 10;
            atomicAdd(&stats[b * 2],     red[0] + red[2] + red[4] + red[6]);
            atomicAdd(&stats[b * 2 + 1], red[1] + red[3] + red[5] + red[7]);
        }
    }
}

// fused projection GEMM: routes Q (x0.125) / K / V(transposed) by 512-col region
// (region = roff + (nt>>3) since BN=64: 8 n-tiles per 512-col region)
__global__ __launch_bounds__(256)
void mgemm_qkv_k(const bf16* __restrict__ A, const bf16* __restrict__ Wbase,
                 const void* __restrict__ bq, const void* __restrict__ bk, const void* __restrict__ bv,
                 bf16* __restrict__ qout, bf16* __restrict__ kout, bf16* __restrict__ vtout,
                 int Gx, int roff, const int* __restrict__ bflag)
{
    __shared__ bf16 As[4 * 4096];
    __shared__ bf16 Bs[4 * 4096];
    const int lin = blockIdx.x;
    const int mt = (lin & 7) * 16 + (lin >> 3) / Gx;
    const int nt = (lin >> 3) % Gx;
    const int m0 = mt * 64, n0 = nt * 64;

    f32x4 acc[2][2];
#pragma unroll
    for (int i = 0; i < 2; ++i)
#pragma unroll
        for (int j = 0; j < 2; ++j) acc[i][j] = (f32x4){0.f, 0.f, 0.f, 0.f};

    gemm_core(A, Wbase, 512, m0, n0, As, Bs, acc);

    const int tid = threadIdx.x;
    const int lane = tid & 63, w = tid >> 6;
    const int wr = w >> 1, wc = w & 1;
    const int l16 = lane & 15, quad = lane >> 4;
    const int bf = bflag[0];
    const int region = roff + (nt >> 3);
    const void* bptr = region == 0 ? bq : (region == 1 ? bk : bv);

#pragma unroll
    for (int i = 0; i < 2; ++i) {
        const int row = m0 + wr * 32 + i * 16 + quad * 4;
#pragma unroll
        for (int j = 0; j < 2; ++j) {
            const int col = n0 + wc * 32 + j * 16 + l16;
            const int colr = col & 511;
            const float bvv = ldmix(bptr, colr, bf);
#pragma unroll
            for (int r = 0; r < 4; ++r) {
                const int rr = row + r;
                float c = acc[i][j][r] + bvv;
                if (region == 0) {
                    qout[(size_t)rr * 512 + colr] = __float2bfloat16(c * 0.125f);
                } else if (region == 1) {
                    kout[(size_t)rr * 512 + colr] = __float2bfloat16(c);
                } else {
                    const int b = rr >> 10, key = rr & 1023;
                    vtout[((size_t)(b * 512 + colr) << 10) | key] = __float2bfloat16(c);
                }
            }
        }
    }
}

// ---------------- MFMA flash attention, fixed-max softmax ----------------
// 1-D grid 1024: xcd=lin&7 owns 8 heads; all 16 q-tiles of a head on one XCD.
__global__ __launch_bounds__(256)
void mfattn_k(const bf16* __restrict__ Q, const bf16* __restrict__ Kb,
              const bf16* __restrict__ Vt, const float* __restrict__ maskf,
              bf16* __restrict__ O)
{
    const int lin = blockIdx.x;
    const int j = lin >> 3, xcd = lin & 7;
    const int head = xcd * 8 + (j >> 4);
    const int qt = j & 15;
    const int b = head >> 3, h = head & 7, s0 = qt * 64;
    const int tid = threadIdx.x;
    const int lane = tid & 63, w = tid >> 6;
    const int l16 = lane & 15, quad = lane >> 4;
    const int bS = b * S_, hc = h * DK_;
    const size_t vtb = (size_t)(b * H_ + h) * (DK_ * S_);

    __shared__ bf16 QPs[64 * 72];
    __shared__ bf16 Ks[64 * 72];
    __shared__ bf16 Vs[64 * 72];

    const int str = tid >> 3;
    const int stc = (tid & 7) * 8;

    *(uint4*)&QPs[str * 72 + stc]        = *(const uint4*)&Q[(size_t)(bS + s0 + str) * D_ + hc + stc];
    *(uint4*)&QPs[(str + 32) * 72 + stc] = *(const uint4*)&Q[(size_t)(bS + s0 + str + 32) * D_ + hc + stc];
    __syncthreads();

    const bf16x8 aq0 = *(const bf16x8*)&QPs[(w * 16 + l16) * 72 + quad * 8];
    const bf16x8 aq1 = *(const bf16x8*)&QPs[(w * 16 + l16) * 72 + quad * 8 + 32];

    f32x4 acc_o[4];
#pragma unroll
    for (int nb = 0; nb < 4; ++nb) acc_o[nb] = (f32x4){0.f, 0.f, 0.f, 0.f};
    float lrow[4] = {0.f, 0.f, 0.f, 0.f};

    for (int t0 = 0; t0 < S_; t0 += 64) {
        __syncthreads();
        *(uint4*)&Ks[str * 72 + stc]        = *(const uint4*)&Kb[(size_t)(bS + t0 + str) * D_ + hc + stc];
        *(uint4*)&Ks[(str + 32) * 72 + stc] = *(const uint4*)&Kb[(size_t)(bS + t0 + str + 32) * D_ + hc + stc];
        *(uint4*)&Vs[str * 72 + stc]        = *(const uint4*)&Vt[vtb + (size_t)str * S_ + t0 + stc];
        *(uint4*)&Vs[(str + 32) * 72 + stc] = *(const uint4*)&Vt[vtb + (size_t)(str + 32) * S_ + t0 + stc];
        __syncthreads();

        f32x4 sacc[4];
#pragma unroll
        for (int nb = 0; nb < 4; ++nb) sacc[nb] = (f32x4){0.f, 0.f, 0.f, 0.f};
#pragma unroll
        for (int nb = 0; nb < 4; ++nb) {
            const bf16x8 b0 = *(const bf16x8*)&Ks[(nb * 16 + l16) * 72 + quad * 8];
            const bf16x8 b1 = *(const bf16x8*)&Ks[(nb * 16 + l16) * 72 + quad * 8 + 32];
            sacc[nb] = __builtin_amdgcn_mfma_f32_16x16x32_bf16(aq0, b0, sacc[nb], 0, 0, 0);
            sacc[nb] = __builtin_amdgcn_mfma_f32_16x16x32_bf16(aq1, b1, sacc[nb], 0, 0, 0);
        }

#pragma unroll
        for (int nb = 0; nb < 4; ++nb) {
            const float mv = maskf[bS + t0 + nb * 16 + l16];
#pragma unroll
            for (int r = 0; r < 4; ++r) {
                const float p = __expf(sacc[nb][r] + mv);
                lrow[r] += p;
                QPs[(w * 16 + quad * 4 + r) * 72 + nb * 16 + l16] = __float2bfloat16(p);
            }
        }

        const bf16x8 ap0 = *(const bf16x8*)&QPs[(w * 16 + l16) * 72 + quad * 8];
        const bf16x8 ap1 = *(const bf16x8*)&QPs[(w * 16 + l16) * 72 + quad * 8 + 32];
#pragma unroll
        for (int nb = 0; nb < 4; ++nb) {
            const bf16x8 v0 = *(const bf16x8*)&Vs[(nb * 16 + l16) * 72 + quad * 8];
            const bf16x8 v1 = *(const bf16x8*)&Vs[(nb * 16 + l16) * 72 + quad * 8 + 32];
            acc_o[nb] = __builtin_amdgcn_mfma_f32_16x16x32_bf16(ap0, v0, acc_o[nb], 0, 0, 0);
            acc_o[nb] = __builtin_amdgcn_mfma_f32_16x16x32_bf16(ap1, v1, acc_o[nb], 0, 0, 0);
        }
    }

#pragma unroll
    for (int r = 0; r < 4; ++r) {
        float ls = lrow[r];
#pragma unroll
        for (int off = 8; off; off >>= 1) ls += __shfl_xor(ls, off);
        const float invl = 1.0f / ls;
        const size_t row = (size_t)(bS + s0 + w * 16 + quad * 4 + r) * D_;
#pragma unroll
        for (int nb = 0; nb < 4; ++nb)
            O[row + hc + nb * 16 + l16] = __float2bfloat16(acc_o[nb][r] * invl);
    }
}

// ---------------- LayerNorm apply (stats already accumulated by GEMM epilogues) ----------------
template <bool FINAL>
__global__ __launch_bounds__(256)
void ln_apply_k(const float* __restrict__ Z, const float* __restrict__ stats,
                const void* __restrict__ w, const void* __restrict__ bb,
                bf16* __restrict__ outb, void* __restrict__ out_final,
                const int* __restrict__ flag)
{
    const int f = flag[0];
    const int b = blockIdx.y;
    const int i4 = (blockIdx.x * 256 + threadIdx.x) * 4;
    const float n = (float)(S_ * D_);
    const float m = stats[b * 2] / n;
    const float var = stats[b * 2 + 1] / n - m * m;
    const float inv = rsqrtf(var + 1e-6f);
    const size_t g = (size_t)b * (S_ * D_) + i4;
    const float4 z = *(const float4*)&Z[g];
    float v[4];
    v[0] = (z.x - m) * inv * ldmix(w, i4 + 0, f) + ldmix(bb, i4 + 0, f);
    v[1] = (z.y - m) * inv * ldmix(w, i4 + 1, f) + ldmix(bb, i4 + 1, f);
    v[2] = (z.z - m) * inv * ldmix(w, i4 + 2, f) + ldmix(bb, i4 + 2, f);
    v[3] = (z.w - m) * inv * ldmix(w, i4 + 3, f) + ldmix(bb, i4 + 3, f);
    union { ushort4 u4; unsigned short u[4]; } ov;
#pragma unroll
    for (int k = 0; k < 4; ++k) {
        bf16 t = __float2bfloat16(v[k]);
        __builtin_memcpy(&ov.u[k], &t, 2);
    }
    if constexpr (FINAL) {
        if (f) *(ushort4*)&((bf16*)out_final)[g] = ov.u4;
        else   *(float4*)&((float*)out_final)[g] = make_float4(v[0], v[1], v[2], v[3]);
    } else {
        *(ushort4*)&outb[g] = ov.u4;
    }
}

// ---------------- orchestration ----------------
extern "C" void kernel_launch(void* const* d_in, const int* in_sizes, int n_in,
                              void* d_out, int out_size, void* d_ws, size_t ws_size,
                              hipStream_t stream)
{
    (void)in_sizes; (void)n_in; (void)out_size; (void)ws_size;

    const void* x        = d_in[0];
    const void* y        = d_in[1];
    const int*  src_mask = (const int*) d_in[2];
    const int*  trg_mask = (const int*) d_in[3];
    const void* m1_wq = d_in[4];
    const void* m1_bq = d_in[5];
    const void* m1_wk = d_in[6];
    const void* m1_bk = d_in[7];
    const void* m1_wv = d_in[8];
    const void* m1_bv = d_in[9];
    const void* m1_wo = d_in[10];
    const void* m1_bo = d_in[11];
    const void* m2_wq = d_in[12];
    const void* m2_bq = d_in[13];
    const void* m2_wk = d_in[14];
    const void* m2_bk = d_in[15];
    const void* m2_wv = d_in[16];
    const void* m2_bv = d_in[17];
    const void* m2_wo = d_in[18];
    const void* m2_bo = d_in[19];
    const void* pw1   = d_in[20];
    const void* pb1   = d_in[21];
    const void* pw2   = d_in[22];
    const void* pb2   = d_in[23];
    const void* ln1_w = d_in[24];
    const void* ln1_b = d_in[25];
    const void* ln2_w = d_in[26];
    const void* ln2_b = d_in[27];
    const void* ln3_w = d_in[28];
    const void* ln3_b = d_in[29];

    const size_t NACT = (size_t)8192 * 512;

    float* zb    = (float*)d_ws;
    float* stats = zb + NACT;
    int*   flag  = (int*)(stats + 48);
    float* trgf  = stats + 64;
    float* srcf  = trgf + 8192;
    bf16* xb16 = (bf16*)(srcf + 8192);
    bf16* yb16 = xb16 + NACT;
    bf16* qb   = yb16 + NACT;
    bf16* kb   = qb   + NACT;
    bf16* vbT  = kb   + NACT;
    bf16* aob  = vbT  + NACT;
    bf16* x1b  = aob  + NACT;
    bf16* x2b  = x1b  + NACT;
    bf16* ffb  = x2b  + NACT;
    bf16* Wq1r = ffb  + (size_t)8192 * 2048;
    bf16* Wq2r = Wq1r + 3 * 262144;
    bf16* Wo1b = Wq1r + 6 * 262144;
    bf16* Wo2b = Wo1b + 262144;
    bf16* W1b  = Wo2b + 262144;
    bf16* W2b  = W1b  + 1048576;

    detect_k<<<1, 64, 0, stream>>>((const unsigned short*)x, stats, flag);
    maskf_k<<<64, 256, 0, stream>>>(trg_mask, src_mask, trgf, srcf);
    convxy_k<<<4096, 256, 0, stream>>>(x, y, xb16, yb16, flag);
    repack6_k<<<6144, 256, 0, stream>>>(m1_wq, m1_wk, m1_wv, m2_wq, m2_wk, m2_wv, Wq1r, flag);
    convw4_k<<<1280, 256, 0, stream>>>(m1_wo, m2_wo, pw1, pw2, Wo1b, flag);

    const dim3 blk(256);
    const dim3 gln(512, B_);

    // ---- self-attention ----
    mgemm_qkv_k<<<dim3(3072), blk, 0, stream>>>(xb16, Wq1r, m1_bq, m1_bk, m1_bv, qb, kb, vbT, 24, 0, flag);
    mfattn_k<<<dim3(1024), blk, 0, stream>>>(qb, kb, vbT, trgf, aob);
    mgemm_k<true, false, true, float><<<dim3(1024), blk, 0, stream>>>(aob, Wo1b, m1_bo, x, zb, 512, 512, 8, flag, flag, stats);
    ln_apply_k<false><<<gln, blk, 0, stream>>>(zb, stats, ln1_w, ln1_b, x1b, nullptr, flag);

    // ---- cross-attention ----
    mgemm_qkv_k<<<dim3(1024), blk, 0, stream>>>(x1b, Wq2r, m2_bq, m2_bk, m2_bv, qb, kb, vbT, 8, 0, flag);
    mgemm_qkv_k<<<dim3(2048), blk, 0, stream>>>(yb16, Wq2r + 262144, m2_bq, m2_bk, m2_bv, qb, kb, vbT, 16, 1, flag);
    mfattn_k<<<dim3(1024), blk, 0, stream>>>(qb, kb, vbT, srcf, aob);
    mgemm_k<true, false, true, float><<<dim3(1024), blk, 0, stream>>>(aob, Wo2b, m2_bo, x1b, zb, 512, 512, 8, flag, flag + 1, stats + 16);
    ln_apply_k<false><<<gln, blk, 0, stream>>>(zb, stats + 16, ln2_w, ln2_b, x2b, nullptr, flag);

    // ---- FFN ----
    mgemm_k<false, true, false, bf16><<<dim3(4096), blk, 0, stream>>>(x2b, W1b, pb1, nullptr, ffb, 2048, 512, 32, flag, flag, nullptr);
    mgemm_k<true, false, true, float><<<dim3(1024), blk, 0, stream>>>(ffb, W2b, pb2, x2b, zb, 512, 2048, 8, flag, flag + 1, stats + 32);
    ln_apply_k<true><<<gln, blk, 0, stream>>>(zb, stats + 32, ln3_w, ln3_b, nullptr, d_out, flag);
}

// Round 16
// 512.919 us; speedup vs baseline: 1.1106x; 1.1106x over previous
//
#include <hip/hip_runtime.h>
#include <hip/hip_bf16.h>

#define B_   8
#define S_   1024
#define D_   512
#define H_   8
#define DK_  64
#define DFF_ 2048

typedef __hip_bfloat16 bf16;
typedef __attribute__((ext_vector_type(8))) short bf16x8;
typedef __attribute__((ext_vector_type(4))) float f32x4;

// flag==1 -> bf16 data; flag==0 -> fp32 data
__device__ __forceinline__ float ldmix(const void* p, size_t i, int f) {
    return f ? __bfloat162float(((const bf16*)p)[i]) : ((const float*)p)[i];
}
__device__ __forceinline__ void store_o(float* p, float v) { *p = v; }
__device__ __forceinline__ void store_o(bf16* p, float v)  { *p = __float2bfloat16(v); }

// async global->LDS, 16B per lane; lds base wave-uniform (lane*16 implicit)
__device__ __forceinline__ void gl_lds16(const void* g, void* l) {
    __builtin_amdgcn_global_load_lds(
        (const __attribute__((address_space(1))) unsigned int*)g,
        (__attribute__((address_space(3))) unsigned int*)l, 16, 0, 0);
}

#define WAITV(N)  asm volatile("s_waitcnt vmcnt(" #N ")" ::: "memory")
#define WAITLGKM0 asm volatile("s_waitcnt lgkmcnt(0)" ::: "memory")

// ---------------- detect dtype + zero LN stats + constants ----------------
__global__ __launch_bounds__(64) void detect_k(const unsigned short* __restrict__ x,
                                               float* __restrict__ stats,
                                               int* __restrict__ flag)
{
    if (threadIdx.x < 48) stats[threadIdx.x] = 0.f;
    int cnt = 0;
    for (int i = threadIdx.x; i < 4096; i += 64) {
        int e = (x[i] >> 7) & 0xFF;
        if (e >= 0xC0) cnt++;
    }
#pragma unroll
    for (int off = 32; off; off >>= 1) cnt += __shfl_xor(cnt, off);
    if (threadIdx.x == 0) { flag[0] = (cnt > 16) ? 0 : 1; flag[1] = 1; }
}

// ---------------- masks -> additive float ----------------
__global__ __launch_bounds__(256) void maskf_k(const int* __restrict__ trg,
                                               const int* __restrict__ src,
                                               float* __restrict__ trgf,
                                               float* __restrict__ srcf)
{
    int i = blockIdx.x * 256 + threadIdx.x;
    if (i < 8192) trgf[i] = trg[i] ? 0.f : -1.0e10f;
    else          srcf[i - 8192] = src[i - 8192] ? 0.f : -1.0e10f;
}

// ---------------- x,y -> bf16 (8 elems/thread; pure copy when already bf16) ----------------
__global__ __launch_bounds__(256) void convxy_k(const void* __restrict__ x,
                                                const void* __restrict__ y,
                                                bf16* __restrict__ xb, bf16* __restrict__ yb,
                                                const int* __restrict__ flag)
{
    const int f = flag[0];
    const int N8 = 8192 * 512 / 8;   // 524288
    int i = blockIdx.x * 256 + threadIdx.x;
    const void* src; bf16* dst; size_t base;
    if (i < N8) { src = x; dst = xb; base = (size_t)i * 8; }
    else        { src = y; dst = yb; base = (size_t)(i - N8) * 8; }
    if (f) {
        *(uint4*)(dst + base) = *(const uint4*)((const bf16*)src + base);
    } else {
        const float4 a = *(const float4*)((const float*)src + base);
        const float4 b = *(const float4*)((const float*)src + base + 4);
        bf16 o[8] = {__float2bfloat16(a.x), __float2bfloat16(a.y),
                     __float2bfloat16(a.z), __float2bfloat16(a.w),
                     __float2bfloat16(b.x), __float2bfloat16(b.y),
                     __float2bfloat16(b.z), __float2bfloat16(b.w)};
        *(uint4*)(dst + base) = *(uint4*)o;
    }
}

// ---------------- 6 qkv weight repacks: in[h,d,k] -> out[(h*64+k), d] ----------------
__global__ __launch_bounds__(256) void repack6_k(const void* __restrict__ w0, const void* __restrict__ w1,
                                                 const void* __restrict__ w2, const void* __restrict__ w3,
                                                 const void* __restrict__ w4, const void* __restrict__ w5,
                                                 bf16* __restrict__ out, const int* __restrict__ flag)
{
    const int f = flag[0];
    const int widx = blockIdx.x >> 10;
    const int j = ((blockIdx.x & 1023) << 8) + threadIdx.x;
    const void* in = widx == 0 ? w0 : widx == 1 ? w1 : widx == 2 ? w2
                   : widx == 3 ? w3 : widx == 4 ? w4 : w5;
    int n = j >> 9, d = j & 511;
    int h = n >> 6, k = n & 63;
    out[(size_t)widx * 262144 + j] =
        __float2bfloat16(ldmix(in, (size_t)h * (D_ * DK_) + (size_t)d * DK_ + k, f));
}

// ---------------- 4 [N][K] weight converts (8 elems/thread) ----------------
__global__ __launch_bounds__(256) void convw4_k(const void* __restrict__ wo1, const void* __restrict__ wo2,
                                                const void* __restrict__ pw1, const void* __restrict__ pw2,
                                                bf16* __restrict__ out, const int* __restrict__ flag)
{
    const int f = flag[0];
    const size_t i8 = (size_t)(blockIdx.x * 256 + threadIdx.x) * 8;   // < 2621440
    const void* in; size_t off;
    if (i8 < 262144)       { in = wo1; off = 0; }
    else if (i8 < 524288)  { in = wo2; off = 262144; }
    else if (i8 < 1572864) { in = pw1; off = 524288; }
    else                   { in = pw2; off = 1572864; }
    const size_t s = i8 - off;
    if (f) {
        *(uint4*)(out + i8) = *(const uint4*)((const bf16*)in + s);
    } else {
        const float4 a = *(const float4*)((const float*)in + s);
        const float4 b = *(const float4*)((const float*)in + s + 4);
        bf16 o[8] = {__float2bfloat16(a.x), __float2bfloat16(a.y),
                     __float2bfloat16(a.z), __float2bfloat16(a.w),
                     __float2bfloat16(b.x), __float2bfloat16(b.y),
                     __float2bfloat16(b.z), __float2bfloat16(b.w)};
        *(uint4*)(out + i8) = *(uint4*)o;
    }
}

// ==================== MFMA GEMM core (templated BN = NB*32) ====================
// BM=128, BK=32; 4 waves 2x2; wave tile 64 x (NB*16). global_load_lds 16B staging,
// XOR-swizzled LDS (granule q = g ^ ((row>>1)&3)), 0 bank conflicts (R8-verified).
// T3+T4 pipeline: prefetch depth PF (2 for NB==2, 1 for NB==4), raw s_barrier +
// counted inline-asm vmcnt (never drained to 0 in the main loop). The trailing
// barrier of iter t protects buffer (t+PF)%NBUF (staged at iter t+1, == buffer
// read at iter t-1's rotation) from write-before-read-done races.
// [R14 post-mortem: A-to-registers variant raced on graph replay (nondeterministic
// output) -- reverted to this exact R3-measured known-good source: 518.96us, passed.]
template <int NB>
__device__ __forceinline__ void gemm_core(const bf16* __restrict__ A, const bf16* __restrict__ Wt,
                                          int K, int m0, int n0, bf16* As, bf16* Bs,
                                          f32x4 (&acc)[4][NB])
{
    constexpr int PF   = (NB == 2) ? 2 : 1;   // prefetch depth
    constexpr int NBUF = PF + 1;              // LDS buffers
    const int tid = threadIdx.x;
    const int lane = tid & 63, w = tid >> 6;
    const int wr = w >> 1, wc = w & 1;
    const int l16 = lane & 15, quad = lane >> 4;
    const int r0 = tid >> 2;
    const int g0 = (tid & 3) ^ ((r0 >> 1) & 3);
    const bf16* pa0 = A + (size_t)(m0 + r0) * K + g0 * 8;
    const bf16* pa1 = pa0 + (size_t)64 * K;
    const bf16* pb0 = Wt + (size_t)(n0 + r0) * K + g0 * 8;
    const bf16* pb1 = pb0 + (size_t)64 * K;

    int aoff[4], boff[NB];
#pragma unroll
    for (int i = 0; i < 4; ++i) {
        const int ra = wr * 64 + i * 16 + l16;
        aoff[i] = ra * 32 + (quad ^ ((ra >> 1) & 3)) * 8;
    }
#pragma unroll
    for (int j = 0; j < NB; ++j) {
        const int rb = wc * (NB * 16) + j * 16 + l16;
        boff[j] = rb * 32 + (quad ^ ((rb >> 1) & 3)) * 8;
    }

    // per-wave loads per stage: 3 (NB==2) or 4 (NB==4)
    auto stage = [&](int bi, int k0) {
        bf16* a = As + bi * 4096;
        bf16* b = Bs + bi * (NB * 1024);
        gl_lds16(pa0 + k0, a + w * 512);
        gl_lds16(pa1 + k0, a + 2048 + w * 512);
        gl_lds16(pb0 + k0, b + w * 512);
        if constexpr (NB == 4) gl_lds16(pb1 + k0, b + 2048 + w * 512);
    };

    const int NT = K >> 5;
    stage(0, 0);
    if constexpr (PF == 2) stage(1, 32);
    int cur = 0, nxt = PF;

    for (int t = 0; t < NT; ++t) {
        if (t + PF < NT) {
            stage(nxt, (t + PF) << 5);
            // in flight beyond current tile: PF stages
            if constexpr (NB == 4) WAITV(4); else WAITV(6);
        } else if (t + 1 < NT) {
            // only reachable when PF==2 (NB==2, 3 loads/stage)
            WAITV(3);
        } else {
            WAITV(0);
        }
        __builtin_amdgcn_s_barrier();
        __builtin_amdgcn_sched_barrier(0);

        const bf16* Ab = As + cur * 4096;
        const bf16* Bb = Bs + cur * (NB * 1024);
        bf16x8 af[4], bg[NB];
#pragma unroll
        for (int i = 0; i < 4; ++i) af[i] = *(const bf16x8*)&Ab[aoff[i]];
#pragma unroll
        for (int j = 0; j < NB; ++j) bg[j] = *(const bf16x8*)&Bb[boff[j]];
#pragma unroll
        for (int i = 0; i < 4; ++i)
#pragma unroll
            for (int j = 0; j < NB; ++j)
                acc[i][j] = __builtin_amdgcn_mfma_f32_16x16x32_bf16(af[i], bg[j], acc[i][j], 0, 0, 0);

        WAITLGKM0;
        __builtin_amdgcn_sched_barrier(0);
        __builtin_amdgcn_s_barrier();
        cur = (cur + 1 == NBUF) ? 0 : cur + 1;
        nxt = (nxt + 1 == NBUF) ? 0 : nxt + 1;
    }
}

// standard GEMM: C[M,N] = A @ Wt^T + bias (+relu) (+res) (+LN-stats)
// 1-D grid, XCD-stripe mapping: xcd=lin&7 owns an 8-M-tile stripe, N fastest.
template <int NB, bool HAS_RES, bool RELU, bool STATS, typename OutT>
__global__ __launch_bounds__(256)
void mgemm_k(const bf16* __restrict__ A, const bf16* __restrict__ Wt,
             const void* __restrict__ bias, const void* __restrict__ res,
             OutT* __restrict__ C, int N, int K, int Gx,
             const int* __restrict__ bflag, const int* __restrict__ rflag,
             float* __restrict__ stats)
{
    constexpr int NBUF = (NB == 2) ? 3 : 2;
    __shared__ bf16 As[NBUF * 4096];
    __shared__ bf16 Bs[NBUF * NB * 1024];
    const int lin = blockIdx.x;
    const int mt = (lin & 7) * 8 + (lin >> 3) / Gx;
    const int nt = (lin >> 3) % Gx;
    const int m0 = mt * 128, n0 = nt * (NB * 32);

    f32x4 acc[4][NB];
#pragma unroll
    for (int i = 0; i < 4; ++i)
#pragma unroll
        for (int j = 0; j < NB; ++j) acc[i][j] = (f32x4){0.f, 0.f, 0.f, 0.f};

    gemm_core<NB>(A, Wt, K, m0, n0, As, Bs, acc);

    const int tid = threadIdx.x;
    const int lane = tid & 63, w = tid >> 6;
    const int wr = w >> 1, wc = w & 1;
    const int l16 = lane & 15, quad = lane >> 4;
    const int bf = bflag[0];
    int rf = 0;
    if constexpr (HAS_RES) rf = rflag[0];

    float s = 0.f, s2 = 0.f;
#pragma unroll
    for (int i = 0; i < 4; ++i) {
        const int row = m0 + wr * 64 + i * 16 + quad * 4;
#pragma unroll
        for (int j = 0; j < NB; ++j) {
            const int col = n0 + wc * (NB * 16) + j * 16 + l16;
            const float bv = ldmix(bias, col, bf);
#pragma unroll
            for (int r = 0; r < 4; ++r) {
                float c = acc[i][j][r] + bv;
                if constexpr (RELU) c = fmaxf(c, 0.f);
                if constexpr (HAS_RES) c += ldmix(res, (size_t)(row + r) * N + col, rf);
                if constexpr (STATS) { s += c; s2 += c * c; }
                store_o(&C[(size_t)(row + r) * N + col], c);
            }
        }
    }
    if constexpr (STATS) {
#pragma unroll
        for (int off = 32; off; off >>= 1) { s += __shfl_xor(s, off); s2 += __shfl_xor(s2, off); }
        __syncthreads();                     // all waves done with As
        float* red = (float*)As;
        if (lane == 0) { red[w * 2] = s; red[w * 2 + 1] = s2; }
        __syncthreads();
        if (tid == 0) {
            const int b = m0 >> 10;
            atomicAdd(&stats[b * 2],     red[0] + red[2] + red[4] + red[6]);
            atomicAdd(&stats[b * 2 + 1], red[1] + red[3] + red[5] + red[7]);
        }
    }
}

// fused projection GEMM: routes Q (x0.125) / K / V(transposed) by 512-col region
template <int NB, int RSHIFT>
__global__ __launch_bounds__(256)
void mgemm_qkv_k(const bf16* __restrict__ A, const bf16* __restrict__ Wbase,
                 const void* __restrict__ bq, const void* __restrict__ bk, const void* __restrict__ bv,
                 bf16* __restrict__ qout, bf16* __restrict__ kout, bf16* __restrict__ vtout,
                 int Gx, int roff, const int* __restrict__ bflag)
{
    constexpr int NBUF = (NB == 2) ? 3 : 2;
    __shared__ bf16 As[NBUF * 4096];
    __shared__ bf16 Bs[NBUF * NB * 1024];
    const int lin = blockIdx.x;
    const int mt = (lin & 7) * 8 + (lin >> 3) / Gx;
    const int nt = (lin >> 3) % Gx;
    const int m0 = mt * 128, n0 = nt * (NB * 32);

    f32x4 acc[4][NB];
#pragma unroll
    for (int i = 0; i < 4; ++i)
#pragma unroll
        for (int j = 0; j < NB; ++j) acc[i][j] = (f32x4){0.f, 0.f, 0.f, 0.f};

    gemm_core<NB>(A, Wbase, 512, m0, n0, As, Bs, acc);

    const int tid = threadIdx.x;
    const int lane = tid & 63, w = tid >> 6;
    const int wr = w >> 1, wc = w & 1;
    const int l16 = lane & 15, quad = lane >> 4;
    const int bf = bflag[0];
    const int region = roff + (nt >> RSHIFT);
    const void* bptr = region == 0 ? bq : (region == 1 ? bk : bv);

#pragma unroll
    for (int i = 0; i < 4; ++i) {
        const int row = m0 + wr * 64 + i * 16 + quad * 4;
#pragma unroll
        for (int j = 0; j < NB; ++j) {
            const int col = n0 + wc * (NB * 16) + j * 16 + l16;
            const int colr = col & 511;
            const float bvv = ldmix(bptr, colr, bf);
#pragma unroll
            for (int r = 0; r < 4; ++r) {
                const int rr = row + r;
                float c = acc[i][j][r] + bvv;
                if (region == 0) {
                    qout[(size_t)rr * 512 + colr] = __float2bfloat16(c * 0.125f);
                } else if (region == 1) {
                    kout[(size_t)rr * 512 + colr] = __float2bfloat16(c);
                } else {
                    const int b = rr >> 10, key = rr & 1023;
                    vtout[((size_t)(b * 512 + colr) << 10) | key] = __float2bfloat16(c);
                }
            }
        }
    }
}

// ---------------- MFMA flash attention, fixed-max softmax ----------------
// 1-D grid 1024: xcd=lin&7 owns 8 heads; all 16 q-tiles of a head on one XCD.
__global__ __launch_bounds__(256)
void mfattn_k(const bf16* __restrict__ Q, const bf16* __restrict__ Kb,
              const bf16* __restrict__ Vt, const float* __restrict__ maskf,
              bf16* __restrict__ O)
{
    const int lin = blockIdx.x;
    const int j = lin >> 3, xcd = lin & 7;
    const int head = xcd * 8 + (j >> 4);
    const int qt = j & 15;
    const int b = head >> 3, h = head & 7, s0 = qt * 64;
    const int tid = threadIdx.x;
    const int lane = tid & 63, w = tid >> 6;
    const int l16 = lane & 15, quad = lane >> 4;
    const int bS = b * S_, hc = h * DK_;
    const size_t vtb = (size_t)(b * H_ + h) * (DK_ * S_);

    __shared__ bf16 QPs[64 * 72];
    __shared__ bf16 Ks[64 * 72];
    __shared__ bf16 Vs[64 * 72];

    const int str = tid >> 3;
    const int stc = (tid & 7) * 8;

    *(uint4*)&QPs[str * 72 + stc]        = *(const uint4*)&Q[(size_t)(bS + s0 + str) * D_ + hc + stc];
    *(uint4*)&QPs[(str + 32) * 72 + stc] = *(const uint4*)&Q[(size_t)(bS + s0 + str + 32) * D_ + hc + stc];
    __syncthreads();

    const bf16x8 aq0 = *(const bf16x8*)&QPs[(w * 16 + l16) * 72 + quad * 8];
    const bf16x8 aq1 = *(const bf16x8*)&QPs[(w * 16 + l16) * 72 + quad * 8 + 32];

    f32x4 acc_o[4];
#pragma unroll
    for (int nb = 0; nb < 4; ++nb) acc_o[nb] = (f32x4){0.f, 0.f, 0.f, 0.f};
    float lrow[4] = {0.f, 0.f, 0.f, 0.f};

    for (int t0 = 0; t0 < S_; t0 += 64) {
        __syncthreads();
        *(uint4*)&Ks[str * 72 + stc]        = *(const uint4*)&Kb[(size_t)(bS + t0 + str) * D_ + hc + stc];
        *(uint4*)&Ks[(str + 32) * 72 + stc] = *(const uint4*)&Kb[(size_t)(bS + t0 + str + 32) * D_ + hc + stc];
        *(uint4*)&Vs[str * 72 + stc]        = *(const uint4*)&Vt[vtb + (size_t)str * S_ + t0 + stc];
        *(uint4*)&Vs[(str + 32) * 72 + stc] = *(const uint4*)&Vt[vtb + (size_t)(str + 32) * S_ + t0 + stc];
        __syncthreads();

        f32x4 sacc[4];
#pragma unroll
        for (int nb = 0; nb < 4; ++nb) sacc[nb] = (f32x4){0.f, 0.f, 0.f, 0.f};
#pragma unroll
        for (int nb = 0; nb < 4; ++nb) {
            const bf16x8 b0 = *(const bf16x8*)&Ks[(nb * 16 + l16) * 72 + quad * 8];
            const bf16x8 b1 = *(const bf16x8*)&Ks[(nb * 16 + l16) * 72 + quad * 8 + 32];
            sacc[nb] = __builtin_amdgcn_mfma_f32_16x16x32_bf16(aq0, b0, sacc[nb], 0, 0, 0);
            sacc[nb] = __builtin_amdgcn_mfma_f32_16x16x32_bf16(aq1, b1, sacc[nb], 0, 0, 0);
        }

#pragma unroll
        for (int nb = 0; nb < 4; ++nb) {
            const float mv = maskf[bS + t0 + nb * 16 + l16];
#pragma unroll
            for (int r = 0; r < 4; ++r) {
                const float p = __expf(sacc[nb][r] + mv);
                lrow[r] += p;
                QPs[(w * 16 + quad * 4 + r) * 72 + nb * 16 + l16] = __float2bfloat16(p);
            }
        }

        const bf16x8 ap0 = *(const bf16x8*)&QPs[(w * 16 + l16) * 72 + quad * 8];
        const bf16x8 ap1 = *(const bf16x8*)&QPs[(w * 16 + l16) * 72 + quad * 8 + 32];
#pragma unroll
        for (int nb = 0; nb < 4; ++nb) {
            const bf16x8 v0 = *(const bf16x8*)&Vs[(nb * 16 + l16) * 72 + quad * 8];
            const bf16x8 v1 = *(const bf16x8*)&Vs[(nb * 16 + l16) * 72 + quad * 8 + 32];
            acc_o[nb] = __builtin_amdgcn_mfma_f32_16x16x32_bf16(ap0, v0, acc_o[nb], 0, 0, 0);
            acc_o[nb] = __builtin_amdgcn_mfma_f32_16x16x32_bf16(ap1, v1, acc_o[nb], 0, 0, 0);
        }
    }

#pragma unroll
    for (int r = 0; r < 4; ++r) {
        float ls = lrow[r];
#pragma unroll
        for (int off = 8; off; off >>= 1) ls += __shfl_xor(ls, off);
        const float invl = 1.0f / ls;
        const size_t row = (size_t)(bS + s0 + w * 16 + quad * 4 + r) * D_;
#pragma unroll
        for (int nb = 0; nb < 4; ++nb)
            O[row + hc + nb * 16 + l16] = __float2bfloat16(acc_o[nb][r] * invl);
    }
}

// ---------------- LayerNorm apply (stats already accumulated by GEMM epilogues) ----------------
template <bool FINAL>
__global__ __launch_bounds__(256)
void ln_apply_k(const float* __restrict__ Z, const float* __restrict__ stats,
                const void* __restrict__ w, const void* __restrict__ bb,
                bf16* __restrict__ outb, void* __restrict__ out_final,
                const int* __restrict__ flag)
{
    const int f = flag[0];
    const int b = blockIdx.y;
    const int i4 = (blockIdx.x * 256 + threadIdx.x) * 4;
    const float n = (float)(S_ * D_);
    const float m = stats[b * 2] / n;
    const float var = stats[b * 2 + 1] / n - m * m;
    const float inv = rsqrtf(var + 1e-6f);
    const size_t g = (size_t)b * (S_ * D_) + i4;
    const float4 z = *(const float4*)&Z[g];
    float v[4];
    v[0] = (z.x - m) * inv * ldmix(w, i4 + 0, f) + ldmix(bb, i4 + 0, f);
    v[1] = (z.y - m) * inv * ldmix(w, i4 + 1, f) + ldmix(bb, i4 + 1, f);
    v[2] = (z.z - m) * inv * ldmix(w, i4 + 2, f) + ldmix(bb, i4 + 2, f);
    v[3] = (z.w - m) * inv * ldmix(w, i4 + 3, f) + ldmix(bb, i4 + 3, f);
    union { ushort4 u4; unsigned short u[4]; } ov;
#pragma unroll
    for (int k = 0; k < 4; ++k) {
        bf16 t = __float2bfloat16(v[k]);
        __builtin_memcpy(&ov.u[k], &t, 2);
    }
    if constexpr (FINAL) {
        if (f) *(ushort4*)&((bf16*)out_final)[g] = ov.u4;
        else   *(float4*)&((float*)out_final)[g] = make_float4(v[0], v[1], v[2], v[3]);
    } else {
        *(ushort4*)&outb[g] = ov.u4;
    }
}

// ---------------- orchestration ----------------
extern "C" void kernel_launch(void* const* d_in, const int* in_sizes, int n_in,
                              void* d_out, int out_size, void* d_ws, size_t ws_size,
                              hipStream_t stream)
{
    (void)in_sizes; (void)n_in; (void)out_size; (void)ws_size;

    const void* x        = d_in[0];
    const void* y        = d_in[1];
    const int*  src_mask = (const int*) d_in[2];
    const int*  trg_mask = (const int*) d_in[3];
    const void* m1_wq = d_in[4];
    const void* m1_bq = d_in[5];
    const void* m1_wk = d_in[6];
    const void* m1_bk = d_in[7];
    const void* m1_wv = d_in[8];
    const void* m1_bv = d_in[9];
    const void* m1_wo = d_in[10];
    const void* m1_bo = d_in[11];
    const void* m2_wq = d_in[12];
    const void* m2_bq = d_in[13];
    const void* m2_wk = d_in[14];
    const void* m2_bk = d_in[15];
    const void* m2_wv = d_in[16];
    const void* m2_bv = d_in[17];
    const void* m2_wo = d_in[18];
    const void* m2_bo = d_in[19];
    const void* pw1   = d_in[20];
    const void* pb1   = d_in[21];
    const void* pw2   = d_in[22];
    const void* pb2   = d_in[23];
    const void* ln1_w = d_in[24];
    const void* ln1_b = d_in[25];
    const void* ln2_w = d_in[26];
    const void* ln2_b = d_in[27];
    const void* ln3_w = d_in[28];
    const void* ln3_b = d_in[29];

    const size_t NACT = (size_t)8192 * 512;

    float* zb    = (float*)d_ws;
    float* stats = zb + NACT;
    int*   flag  = (int*)(stats + 48);
    float* trgf  = stats + 64;
    float* srcf  = trgf + 8192;
    bf16* xb16 = (bf16*)(srcf + 8192);
    bf16* yb16 = xb16 + NACT;
    bf16* qb   = yb16 + NACT;
    bf16* kb   = qb   + NACT;
    bf16* vbT  = kb   + NACT;
    bf16* aob  = vbT  + NACT;
    bf16* x1b  = aob  + NACT;
    bf16* x2b  = x1b  + NACT;
    bf16* ffb  = x2b  + NACT;
    bf16* Wq1r = ffb  + (size_t)8192 * 2048;
    bf16* Wq2r = Wq1r + 3 * 262144;
    bf16* Wo1b = Wq1r + 6 * 262144;
    bf16* Wo2b = Wo1b + 262144;
    bf16* W1b  = Wo2b + 262144;
    bf16* W2b  = W1b  + 1048576;

    detect_k<<<1, 64, 0, stream>>>((const unsigned short*)x, stats, flag);
    maskf_k<<<64, 256, 0, stream>>>(trg_mask, src_mask, trgf, srcf);
    convxy_k<<<4096, 256, 0, stream>>>(x, y, xb16, yb16, flag);
    repack6_k<<<6144, 256, 0, stream>>>(m1_wq, m1_wk, m1_wv, m2_wq, m2_wk, m2_wv, Wq1r, flag);
    convw4_k<<<1280, 256, 0, stream>>>(m1_wo, m2_wo, pw1, pw2, Wo1b, flag);

    const dim3 blk(256);
    const dim3 gln(512, B_);

    // ---- self-attention ----
    mgemm_qkv_k<4, 2><<<dim3(12 * 64), blk, 0, stream>>>(xb16, Wq1r, m1_bq, m1_bk, m1_bv, qb, kb, vbT, 12, 0, flag);
    mfattn_k<<<dim3(1024), blk, 0, stream>>>(qb, kb, vbT, trgf, aob);
    mgemm_k<2, true, false, true, float><<<dim3(8 * 64), blk, 0, stream>>>(aob, Wo1b, m1_bo, x, zb, 512, 512, 8, flag, flag, stats);
    ln_apply_k<false><<<gln, blk, 0, stream>>>(zb, stats, ln1_w, ln1_b, x1b, nullptr, flag);

    // ---- cross-attention ----
    mgemm_qkv_k<2, 3><<<dim3(8 * 64), blk, 0, stream>>>(x1b, Wq2r, m2_bq, m2_bk, m2_bv, qb, kb, vbT, 8, 0, flag);
    mgemm_qkv_k<4, 2><<<dim3(8 * 64), blk, 0, stream>>>(yb16, Wq2r + 262144, m2_bq, m2_bk, m2_bv, qb, kb, vbT, 8, 1, flag);
    mfattn_k<<<dim3(1024), blk, 0, stream>>>(qb, kb, vbT, srcf, aob);
    mgemm_k<2, true, false, true, float><<<dim3(8 * 64), blk, 0, stream>>>(aob, Wo2b, m2_bo, x1b, zb, 512, 512, 8, flag, flag + 1, stats + 16);
    ln_apply_k<false><<<gln, blk, 0, stream>>>(zb, stats + 16, ln2_w, ln2_b, x2b, nullptr, flag);

    // ---- FFN ----
    mgemm_k<4, false, true, false, bf16><<<dim3(16 * 64), blk, 0, stream>>>(x2b, W1b, pb1, nullptr, ffb, 2048, 512, 16, flag, flag, nullptr);
    mgemm_k<2, true, false, true, float><<<dim3(8 * 64), blk, 0, stream>>>(ffb, W2b, pb2, x2b, zb, 512, 2048, 8, flag, flag + 1, stats + 32);
    ln_apply_k<true><<<gln, blk, 0, stream>>>(zb, stats + 32, ln3_w, ln3_b, nullptr, d_out, flag);
}

// Round 17
// 508.918 us; speedup vs baseline: 1.1193x; 1.0079x over previous
//
#include <hip/hip_runtime.h>
#include <hip/hip_bf16.h>

#define B_   8
#define S_   1024
#define D_   512
#define H_   8
#define DK_  64
#define DFF_ 2048

typedef __hip_bfloat16 bf16;
typedef __attribute__((ext_vector_type(8))) short bf16x8;
typedef __attribute__((ext_vector_type(4))) float f32x4;

// flag==1 -> bf16 data; flag==0 -> fp32 data
__device__ __forceinline__ float ldmix(const void* p, size_t i, int f) {
    return f ? __bfloat162float(((const bf16*)p)[i]) : ((const float*)p)[i];
}
__device__ __forceinline__ void store_o(float* p, float v) { *p = v; }
__device__ __forceinline__ void store_o(bf16* p, float v)  { *p = __float2bfloat16(v); }

// async global->LDS, 16B per lane; lds base wave-uniform (lane*16 implicit)
__device__ __forceinline__ void gl_lds16(const void* g, void* l) {
    __builtin_amdgcn_global_load_lds(
        (const __attribute__((address_space(1))) unsigned int*)g,
        (__attribute__((address_space(3))) unsigned int*)l, 16, 0, 0);
}

#define WAITV(N)  asm volatile("s_waitcnt vmcnt(" #N ")" ::: "memory")
#define WAITLGKM0 asm volatile("s_waitcnt lgkmcnt(0)" ::: "memory")

// ---------------- detect dtype + zero LN stats + constants ----------------
__global__ __launch_bounds__(64) void detect_k(const unsigned short* __restrict__ x,
                                               float* __restrict__ stats,
                                               int* __restrict__ flag)
{
    if (threadIdx.x < 48) stats[threadIdx.x] = 0.f;
    int cnt = 0;
    for (int i = threadIdx.x; i < 4096; i += 64) {
        int e = (x[i] >> 7) & 0xFF;
        if (e >= 0xC0) cnt++;
    }
#pragma unroll
    for (int off = 32; off; off >>= 1) cnt += __shfl_xor(cnt, off);
    if (threadIdx.x == 0) { flag[0] = (cnt > 16) ? 0 : 1; flag[1] = 1; }
}

// ---------------- masks -> additive float ----------------
__global__ __launch_bounds__(256) void maskf_k(const int* __restrict__ trg,
                                               const int* __restrict__ src,
                                               float* __restrict__ trgf,
                                               float* __restrict__ srcf)
{
    int i = blockIdx.x * 256 + threadIdx.x;
    if (i < 8192) trgf[i] = trg[i] ? 0.f : -1.0e10f;
    else          srcf[i - 8192] = src[i - 8192] ? 0.f : -1.0e10f;
}

// ---------------- x,y -> bf16 (8 elems/thread; pure copy when already bf16) ----------------
__global__ __launch_bounds__(256) void convxy_k(const void* __restrict__ x,
                                                const void* __restrict__ y,
                                                bf16* __restrict__ xb, bf16* __restrict__ yb,
                                                const int* __restrict__ flag)
{
    const int f = flag[0];
    const int N8 = 8192 * 512 / 8;   // 524288
    int i = blockIdx.x * 256 + threadIdx.x;
    const void* src; bf16* dst; size_t base;
    if (i < N8) { src = x; dst = xb; base = (size_t)i * 8; }
    else        { src = y; dst = yb; base = (size_t)(i - N8) * 8; }
    if (f) {
        *(uint4*)(dst + base) = *(const uint4*)((const bf16*)src + base);
    } else {
        const float4 a = *(const float4*)((const float*)src + base);
        const float4 b = *(const float4*)((const float*)src + base + 4);
        bf16 o[8] = {__float2bfloat16(a.x), __float2bfloat16(a.y),
                     __float2bfloat16(a.z), __float2bfloat16(a.w),
                     __float2bfloat16(b.x), __float2bfloat16(b.y),
                     __float2bfloat16(b.z), __float2bfloat16(b.w)};
        *(uint4*)(dst + base) = *(uint4*)o;
    }
}

// ---------------- 6 qkv weight repacks: in[h,d,k] -> out[(h*64+k), d] ----------------
__global__ __launch_bounds__(256) void repack6_k(const void* __restrict__ w0, const void* __restrict__ w1,
                                                 const void* __restrict__ w2, const void* __restrict__ w3,
                                                 const void* __restrict__ w4, const void* __restrict__ w5,
                                                 bf16* __restrict__ out, const int* __restrict__ flag)
{
    const int f = flag[0];
    const int widx = blockIdx.x >> 10;
    const int j = ((blockIdx.x & 1023) << 8) + threadIdx.x;
    const void* in = widx == 0 ? w0 : widx == 1 ? w1 : widx == 2 ? w2
                   : widx == 3 ? w3 : widx == 4 ? w4 : w5;
    int n = j >> 9, d = j & 511;
    int h = n >> 6, k = n & 63;
    out[(size_t)widx * 262144 + j] =
        __float2bfloat16(ldmix(in, (size_t)h * (D_ * DK_) + (size_t)d * DK_ + k, f));
}

// ---------------- 4 [N][K] weight converts (8 elems/thread) ----------------
__global__ __launch_bounds__(256) void convw4_k(const void* __restrict__ wo1, const void* __restrict__ wo2,
                                                const void* __restrict__ pw1, const void* __restrict__ pw2,
                                                bf16* __restrict__ out, const int* __restrict__ flag)
{
    const int f = flag[0];
    const size_t i8 = (size_t)(blockIdx.x * 256 + threadIdx.x) * 8;   // < 2621440
    const void* in; size_t off;
    if (i8 < 262144)       { in = wo1; off = 0; }
    else if (i8 < 524288)  { in = wo2; off = 262144; }
    else if (i8 < 1572864) { in = pw1; off = 524288; }
    else                   { in = pw2; off = 1572864; }
    const size_t s = i8 - off;
    if (f) {
        *(uint4*)(out + i8) = *(const uint4*)((const bf16*)in + s);
    } else {
        const float4 a = *(const float4*)((const float*)in + s);
        const float4 b = *(const float4*)((const float*)in + s + 4);
        bf16 o[8] = {__float2bfloat16(a.x), __float2bfloat16(a.y),
                     __float2bfloat16(a.z), __float2bfloat16(a.w),
                     __float2bfloat16(b.x), __float2bfloat16(b.y),
                     __float2bfloat16(b.z), __float2bfloat16(b.w)};
        *(uint4*)(out + i8) = *(uint4*)o;
    }
}

// ==================== MFMA GEMM core (templated BN = NB*32) ====================
// BM=128, BK=32; 4 waves 2x2; wave tile 64 x (NB*16). global_load_lds 16B staging,
// XOR-swizzled LDS (granule q = g ^ ((row>>1)&3)), 0 bank conflicts (R8-verified).
// T3+T4 pipeline: prefetch depth PF (2 for NB==2, 1 for NB==4), raw s_barrier +
// counted inline-asm vmcnt (never drained to 0 in the main loop).
// [R16: this exact core measured 512.9us e2e, deterministic. R16 change is
// epilogue-only: zb stored bf16 (was fp32) -- traffic cut, no sync change.]
template <int NB>
__device__ __forceinline__ void gemm_core(const bf16* __restrict__ A, const bf16* __restrict__ Wt,
                                          int K, int m0, int n0, bf16* As, bf16* Bs,
                                          f32x4 (&acc)[4][NB])
{
    constexpr int PF   = (NB == 2) ? 2 : 1;   // prefetch depth
    constexpr int NBUF = PF + 1;              // LDS buffers
    const int tid = threadIdx.x;
    const int lane = tid & 63, w = tid >> 6;
    const int wr = w >> 1, wc = w & 1;
    const int l16 = lane & 15, quad = lane >> 4;
    const int r0 = tid >> 2;
    const int g0 = (tid & 3) ^ ((r0 >> 1) & 3);
    const bf16* pa0 = A + (size_t)(m0 + r0) * K + g0 * 8;
    const bf16* pa1 = pa0 + (size_t)64 * K;
    const bf16* pb0 = Wt + (size_t)(n0 + r0) * K + g0 * 8;
    const bf16* pb1 = pb0 + (size_t)64 * K;

    int aoff[4], boff[NB];
#pragma unroll
    for (int i = 0; i < 4; ++i) {
        const int ra = wr * 64 + i * 16 + l16;
        aoff[i] = ra * 32 + (quad ^ ((ra >> 1) & 3)) * 8;
    }
#pragma unroll
    for (int j = 0; j < NB; ++j) {
        const int rb = wc * (NB * 16) + j * 16 + l16;
        boff[j] = rb * 32 + (quad ^ ((rb >> 1) & 3)) * 8;
    }

    // per-wave loads per stage: 3 (NB==2) or 4 (NB==4)
    auto stage = [&](int bi, int k0) {
        bf16* a = As + bi * 4096;
        bf16* b = Bs + bi * (NB * 1024);
        gl_lds16(pa0 + k0, a + w * 512);
        gl_lds16(pa1 + k0, a + 2048 + w * 512);
        gl_lds16(pb0 + k0, b + w * 512);
        if constexpr (NB == 4) gl_lds16(pb1 + k0, b + 2048 + w * 512);
    };

    const int NT = K >> 5;
    stage(0, 0);
    if constexpr (PF == 2) stage(1, 32);
    int cur = 0, nxt = PF;

    for (int t = 0; t < NT; ++t) {
        if (t + PF < NT) {
            stage(nxt, (t + PF) << 5);
            // in flight beyond current tile: PF stages
            if constexpr (NB == 4) WAITV(4); else WAITV(6);
        } else if (t + 1 < NT) {
            // only reachable when PF==2 (NB==2, 3 loads/stage)
            WAITV(3);
        } else {
            WAITV(0);
        }
        __builtin_amdgcn_s_barrier();
        __builtin_amdgcn_sched_barrier(0);

        const bf16* Ab = As + cur * 4096;
        const bf16* Bb = Bs + cur * (NB * 1024);
        bf16x8 af[4], bg[NB];
#pragma unroll
        for (int i = 0; i < 4; ++i) af[i] = *(const bf16x8*)&Ab[aoff[i]];
#pragma unroll
        for (int j = 0; j < NB; ++j) bg[j] = *(const bf16x8*)&Bb[boff[j]];
#pragma unroll
        for (int i = 0; i < 4; ++i)
#pragma unroll
            for (int j = 0; j < NB; ++j)
                acc[i][j] = __builtin_amdgcn_mfma_f32_16x16x32_bf16(af[i], bg[j], acc[i][j], 0, 0, 0);

        WAITLGKM0;
        __builtin_amdgcn_sched_barrier(0);
        __builtin_amdgcn_s_barrier();
        cur = (cur + 1 == NBUF) ? 0 : cur + 1;
        nxt = (nxt + 1 == NBUF) ? 0 : nxt + 1;
    }
}

// standard GEMM: C[M,N] = A @ Wt^T + bias (+relu) (+res) (+LN-stats)
// 1-D grid, XCD-stripe mapping: xcd=lin&7 owns an 8-M-tile stripe, N fastest.
template <int NB, bool HAS_RES, bool RELU, bool STATS, typename OutT>
__global__ __launch_bounds__(256)
void mgemm_k(const bf16* __restrict__ A, const bf16* __restrict__ Wt,
             const void* __restrict__ bias, const void* __restrict__ res,
             OutT* __restrict__ C, int N, int K, int Gx,
             const int* __restrict__ bflag, const int* __restrict__ rflag,
             float* __restrict__ stats)
{
    constexpr int NBUF = (NB == 2) ? 3 : 2;
    __shared__ bf16 As[NBUF * 4096];
    __shared__ bf16 Bs[NBUF * NB * 1024];
    const int lin = blockIdx.x;
    const int mt = (lin & 7) * 8 + (lin >> 3) / Gx;
    const int nt = (lin >> 3) % Gx;
    const int m0 = mt * 128, n0 = nt * (NB * 32);

    f32x4 acc[4][NB];
#pragma unroll
    for (int i = 0; i < 4; ++i)
#pragma unroll
        for (int j = 0; j < NB; ++j) acc[i][j] = (f32x4){0.f, 0.f, 0.f, 0.f};

    gemm_core<NB>(A, Wt, K, m0, n0, As, Bs, acc);

    const int tid = threadIdx.x;
    const int lane = tid & 63, w = tid >> 6;
    const int wr = w >> 1, wc = w & 1;
    const int l16 = lane & 15, quad = lane >> 4;
    const int bf = bflag[0];
    int rf = 0;
    if constexpr (HAS_RES) rf = rflag[0];

    float s = 0.f, s2 = 0.f;
#pragma unroll
    for (int i = 0; i < 4; ++i) {
        const int row = m0 + wr * 64 + i * 16 + quad * 4;
#pragma unroll
        for (int j = 0; j < NB; ++j) {
            const int col = n0 + wc * (NB * 16) + j * 16 + l16;
            const float bv = ldmix(bias, col, bf);
#pragma unroll
            for (int r = 0; r < 4; ++r) {
                float c = acc[i][j][r] + bv;
                if constexpr (RELU) c = fmaxf(c, 0.f);
                if constexpr (HAS_RES) c += ldmix(res, (size_t)(row + r) * N + col, rf);
                if constexpr (STATS) { s += c; s2 += c * c; }
                store_o(&C[(size_t)(row + r) * N + col], c);
            }
        }
    }
    if constexpr (STATS) {
#pragma unroll
        for (int off = 32; off; off >>= 1) { s += __shfl_xor(s, off); s2 += __shfl_xor(s2, off); }
        __syncthreads();                     // all waves done with As
        float* red = (float*)As;
        if (lane == 0) { red[w * 2] = s; red[w * 2 + 1] = s2; }
        __syncthreads();
        if (tid == 0) {
            const int b = m0 >> 10;
            atomicAdd(&stats[b * 2],     red[0] + red[2] + red[4] + red[6]);
            atomicAdd(&stats[b * 2 + 1], red[1] + red[3] + red[5] + red[7]);
        }
    }
}

// fused projection GEMM: routes Q (x0.125) / K / V(transposed) by 512-col region
template <int NB, int RSHIFT>
__global__ __launch_bounds__(256)
void mgemm_qkv_k(const bf16* __restrict__ A, const bf16* __restrict__ Wbase,
                 const void* __restrict__ bq, const void* __restrict__ bk, const void* __restrict__ bv,
                 bf16* __restrict__ qout, bf16* __restrict__ kout, bf16* __restrict__ vtout,
                 int Gx, int roff, const int* __restrict__ bflag)
{
    constexpr int NBUF = (NB == 2) ? 3 : 2;
    __shared__ bf16 As[NBUF * 4096];
    __shared__ bf16 Bs[NBUF * NB * 1024];
    const int lin = blockIdx.x;
    const int mt = (lin & 7) * 8 + (lin >> 3) / Gx;
    const int nt = (lin >> 3) % Gx;
    const int m0 = mt * 128, n0 = nt * (NB * 32);

    f32x4 acc[4][NB];
#pragma unroll
    for (int i = 0; i < 4; ++i)
#pragma unroll
        for (int j = 0; j < NB; ++j) acc[i][j] = (f32x4){0.f, 0.f, 0.f, 0.f};

    gemm_core<NB>(A, Wbase, 512, m0, n0, As, Bs, acc);

    const int tid = threadIdx.x;
    const int lane = tid & 63, w = tid >> 6;
    const int wr = w >> 1, wc = w & 1;
    const int l16 = lane & 15, quad = lane >> 4;
    const int bf = bflag[0];
    const int region = roff + (nt >> RSHIFT);
    const void* bptr = region == 0 ? bq : (region == 1 ? bk : bv);

#pragma unroll
    for (int i = 0; i < 4; ++i) {
        const int row = m0 + wr * 64 + i * 16 + quad * 4;
#pragma unroll
        for (int j = 0; j < NB; ++j) {
            const int col = n0 + wc * (NB * 16) + j * 16 + l16;
            const int colr = col & 511;
            const float bvv = ldmix(bptr, colr, bf);
#pragma unroll
            for (int r = 0; r < 4; ++r) {
                const int rr = row + r;
                float c = acc[i][j][r] + bvv;
                if (region == 0) {
                    qout[(size_t)rr * 512 + colr] = __float2bfloat16(c * 0.125f);
                } else if (region == 1) {
                    kout[(size_t)rr * 512 + colr] = __float2bfloat16(c);
                } else {
                    const int b = rr >> 10, key = rr & 1023;
                    vtout[((size_t)(b * 512 + colr) << 10) | key] = __float2bfloat16(c);
                }
            }
        }
    }
}

// ---------------- MFMA flash attention, fixed-max softmax ----------------
// 1-D grid 1024: xcd=lin&7 owns 8 heads; all 16 q-tiles of a head on one XCD.
__global__ __launch_bounds__(256)
void mfattn_k(const bf16* __restrict__ Q, const bf16* __restrict__ Kb,
              const bf16* __restrict__ Vt, const float* __restrict__ maskf,
              bf16* __restrict__ O)
{
    const int lin = blockIdx.x;
    const int j = lin >> 3, xcd = lin & 7;
    const int head = xcd * 8 + (j >> 4);
    const int qt = j & 15;
    const int b = head >> 3, h = head & 7, s0 = qt * 64;
    const int tid = threadIdx.x;
    const int lane = tid & 63, w = tid >> 6;
    const int l16 = lane & 15, quad = lane >> 4;
    const int bS = b * S_, hc = h * DK_;
    const size_t vtb = (size_t)(b * H_ + h) * (DK_ * S_);

    __shared__ bf16 QPs[64 * 72];
    __shared__ bf16 Ks[64 * 72];
    __shared__ bf16 Vs[64 * 72];

    const int str = tid >> 3;
    const int stc = (tid & 7) * 8;

    *(uint4*)&QPs[str * 72 + stc]        = *(const uint4*)&Q[(size_t)(bS + s0 + str) * D_ + hc + stc];
    *(uint4*)&QPs[(str + 32) * 72 + stc] = *(const uint4*)&Q[(size_t)(bS + s0 + str + 32) * D_ + hc + stc];
    __syncthreads();

    const bf16x8 aq0 = *(const bf16x8*)&QPs[(w * 16 + l16) * 72 + quad * 8];
    const bf16x8 aq1 = *(const bf16x8*)&QPs[(w * 16 + l16) * 72 + quad * 8 + 32];

    f32x4 acc_o[4];
#pragma unroll
    for (int nb = 0; nb < 4; ++nb) acc_o[nb] = (f32x4){0.f, 0.f, 0.f, 0.f};
    float lrow[4] = {0.f, 0.f, 0.f, 0.f};

    for (int t0 = 0; t0 < S_; t0 += 64) {
        __syncthreads();
        *(uint4*)&Ks[str * 72 + stc]        = *(const uint4*)&Kb[(size_t)(bS + t0 + str) * D_ + hc + stc];
        *(uint4*)&Ks[(str + 32) * 72 + stc] = *(const uint4*)&Kb[(size_t)(bS + t0 + str + 32) * D_ + hc + stc];
        *(uint4*)&Vs[str * 72 + stc]        = *(const uint4*)&Vt[vtb + (size_t)str * S_ + t0 + stc];
        *(uint4*)&Vs[(str + 32) * 72 + stc] = *(const uint4*)&Vt[vtb + (size_t)(str + 32) * S_ + t0 + stc];
        __syncthreads();

        f32x4 sacc[4];
#pragma unroll
        for (int nb = 0; nb < 4; ++nb) sacc[nb] = (f32x4){0.f, 0.f, 0.f, 0.f};
#pragma unroll
        for (int nb = 0; nb < 4; ++nb) {
            const bf16x8 b0 = *(const bf16x8*)&Ks[(nb * 16 + l16) * 72 + quad * 8];
            const bf16x8 b1 = *(const bf16x8*)&Ks[(nb * 16 + l16) * 72 + quad * 8 + 32];
            sacc[nb] = __builtin_amdgcn_mfma_f32_16x16x32_bf16(aq0, b0, sacc[nb], 0, 0, 0);
            sacc[nb] = __builtin_amdgcn_mfma_f32_16x16x32_bf16(aq1, b1, sacc[nb], 0, 0, 0);
        }

#pragma unroll
        for (int nb = 0; nb < 4; ++nb) {
            const float mv = maskf[bS + t0 + nb * 16 + l16];
#pragma unroll
            for (int r = 0; r < 4; ++r) {
                const float p = __expf(sacc[nb][r] + mv);
                lrow[r] += p;
                QPs[(w * 16 + quad * 4 + r) * 72 + nb * 16 + l16] = __float2bfloat16(p);
            }
        }

        const bf16x8 ap0 = *(const bf16x8*)&QPs[(w * 16 + l16) * 72 + quad * 8];
        const bf16x8 ap1 = *(const bf16x8*)&QPs[(w * 16 + l16) * 72 + quad * 8 + 32];
#pragma unroll
        for (int nb = 0; nb < 4; ++nb) {
            const bf16x8 v0 = *(const bf16x8*)&Vs[(nb * 16 + l16) * 72 + quad * 8];
            const bf16x8 v1 = *(const bf16x8*)&Vs[(nb * 16 + l16) * 72 + quad * 8 + 32];
            acc_o[nb] = __builtin_amdgcn_mfma_f32_16x16x32_bf16(ap0, v0, acc_o[nb], 0, 0, 0);
            acc_o[nb] = __builtin_amdgcn_mfma_f32_16x16x32_bf16(ap1, v1, acc_o[nb], 0, 0, 0);
        }
    }

#pragma unroll
    for (int r = 0; r < 4; ++r) {
        float ls = lrow[r];
#pragma unroll
        for (int off = 8; off; off >>= 1) ls += __shfl_xor(ls, off);
        const float invl = 1.0f / ls;
        const size_t row = (size_t)(bS + s0 + w * 16 + quad * 4 + r) * D_;
#pragma unroll
        for (int nb = 0; nb < 4; ++nb)
            O[row + hc + nb * 16 + l16] = __float2bfloat16(acc_o[nb][r] * invl);
    }
}

// ---------------- LayerNorm apply (stats from GEMM epilogues; Z stored bf16) ----------------
template <bool FINAL>
__global__ __launch_bounds__(256)
void ln_apply_k(const bf16* __restrict__ Z, const float* __restrict__ stats,
                const void* __restrict__ w, const void* __restrict__ bb,
                bf16* __restrict__ outb, void* __restrict__ out_final,
                const int* __restrict__ flag)
{
    const int f = flag[0];
    const int b = blockIdx.y;
    const int i4 = (blockIdx.x * 256 + threadIdx.x) * 4;
    const float n = (float)(S_ * D_);
    const float m = stats[b * 2] / n;
    const float var = stats[b * 2 + 1] / n - m * m;
    const float inv = rsqrtf(var + 1e-6f);
    const size_t g = (size_t)b * (S_ * D_) + i4;
    union { ushort4 u4; unsigned short u[4]; } zi;
    zi.u4 = *(const ushort4*)&Z[g];
    float v[4];
#pragma unroll
    for (int k = 0; k < 4; ++k) {
        bf16 t;
        __builtin_memcpy(&t, &zi.u[k], 2);
        v[k] = (__bfloat162float(t) - m) * inv * ldmix(w, i4 + k, f) + ldmix(bb, i4 + k, f);
    }
    union { ushort4 u4; unsigned short u[4]; } ov;
#pragma unroll
    for (int k = 0; k < 4; ++k) {
        bf16 t = __float2bfloat16(v[k]);
        __builtin_memcpy(&ov.u[k], &t, 2);
    }
    if constexpr (FINAL) {
        if (f) *(ushort4*)&((bf16*)out_final)[g] = ov.u4;
        else   *(float4*)&((float*)out_final)[g] = make_float4(v[0], v[1], v[2], v[3]);
    } else {
        *(ushort4*)&outb[g] = ov.u4;
    }
}

// ---------------- orchestration ----------------
extern "C" void kernel_launch(void* const* d_in, const int* in_sizes, int n_in,
                              void* d_out, int out_size, void* d_ws, size_t ws_size,
                              hipStream_t stream)
{
    (void)in_sizes; (void)n_in; (void)out_size; (void)ws_size;

    const void* x        = d_in[0];
    const void* y        = d_in[1];
    const int*  src_mask = (const int*) d_in[2];
    const int*  trg_mask = (const int*) d_in[3];
    const void* m1_wq = d_in[4];
    const void* m1_bq = d_in[5];
    const void* m1_wk = d_in[6];
    const void* m1_bk = d_in[7];
    const void* m1_wv = d_in[8];
    const void* m1_bv = d_in[9];
    const void* m1_wo = d_in[10];
    const void* m1_bo = d_in[11];
    const void* m2_wq = d_in[12];
    const void* m2_bq = d_in[13];
    const void* m2_wk = d_in[14];
    const void* m2_bk = d_in[15];
    const void* m2_wv = d_in[16];
    const void* m2_bv = d_in[17];
    const void* m2_wo = d_in[18];
    const void* m2_bo = d_in[19];
    const void* pw1   = d_in[20];
    const void* pb1   = d_in[21];
    const void* pw2   = d_in[22];
    const void* pb2   = d_in[23];
    const void* ln1_w = d_in[24];
    const void* ln1_b = d_in[25];
    const void* ln2_w = d_in[26];
    const void* ln2_b = d_in[27];
    const void* ln3_w = d_in[28];
    const void* ln3_b = d_in[29];

    const size_t NACT = (size_t)8192 * 512;

    float* zb    = (float*)d_ws;               // region sized NACT floats; stores bf16 now
    bf16*  zb16  = (bf16*)zb;
    float* stats = zb + NACT;
    int*   flag  = (int*)(stats + 48);
    float* trgf  = stats + 64;
    float* srcf  = trgf + 8192;
    bf16* xb16 = (bf16*)(srcf + 8192);
    bf16* yb16 = xb16 + NACT;
    bf16* qb   = yb16 + NACT;
    bf16* kb   = qb   + NACT;
    bf16* vbT  = kb   + NACT;
    bf16* aob  = vbT  + NACT;
    bf16* x1b  = aob  + NACT;
    bf16* x2b  = x1b  + NACT;
    bf16* ffb  = x2b  + NACT;
    bf16* Wq1r = ffb  + (size_t)8192 * 2048;
    bf16* Wq2r = Wq1r + 3 * 262144;
    bf16* Wo1b = Wq1r + 6 * 262144;
    bf16* Wo2b = Wo1b + 262144;
    bf16* W1b  = Wo2b + 262144;
    bf16* W2b  = W1b  + 1048576;

    detect_k<<<1, 64, 0, stream>>>((const unsigned short*)x, stats, flag);
    maskf_k<<<64, 256, 0, stream>>>(trg_mask, src_mask, trgf, srcf);
    convxy_k<<<4096, 256, 0, stream>>>(x, y, xb16, yb16, flag);
    repack6_k<<<6144, 256, 0, stream>>>(m1_wq, m1_wk, m1_wv, m2_wq, m2_wk, m2_wv, Wq1r, flag);
    convw4_k<<<1280, 256, 0, stream>>>(m1_wo, m2_wo, pw1, pw2, Wo1b, flag);

    const dim3 blk(256);
    const dim3 gln(512, B_);

    // ---- self-attention ----
    mgemm_qkv_k<4, 2><<<dim3(12 * 64), blk, 0, stream>>>(xb16, Wq1r, m1_bq, m1_bk, m1_bv, qb, kb, vbT, 12, 0, flag);
    mfattn_k<<<dim3(1024), blk, 0, stream>>>(qb, kb, vbT, trgf, aob);
    mgemm_k<2, true, false, true, bf16><<<dim3(8 * 64), blk, 0, stream>>>(aob, Wo1b, m1_bo, x, zb16, 512, 512, 8, flag, flag, stats);
    ln_apply_k<false><<<gln, blk, 0, stream>>>(zb16, stats, ln1_w, ln1_b, x1b, nullptr, flag);

    // ---- cross-attention ----
    mgemm_qkv_k<2, 3><<<dim3(8 * 64), blk, 0, stream>>>(x1b, Wq2r, m2_bq, m2_bk, m2_bv, qb, kb, vbT, 8, 0, flag);
    mgemm_qkv_k<4, 2><<<dim3(8 * 64), blk, 0, stream>>>(yb16, Wq2r + 262144, m2_bq, m2_bk, m2_bv, qb, kb, vbT, 8, 1, flag);
    mfattn_k<<<dim3(1024), blk, 0, stream>>>(qb, kb, vbT, srcf, aob);
    mgemm_k<2, true, false, true, bf16><<<dim3(8 * 64), blk, 0, stream>>>(aob, Wo2b, m2_bo, x1b, zb16, 512, 512, 8, flag, flag + 1, stats + 16);
    ln_apply_k<false><<<gln, blk, 0, stream>>>(zb16, stats + 16, ln2_w, ln2_b, x2b, nullptr, flag);

    // ---- FFN ----
    mgemm_k<4, false, true, false, bf16><<<dim3(16 * 64), blk, 0, stream>>>(x2b, W1b, pb1, nullptr, ffb, 2048, 512, 16, flag, flag, nullptr);
    mgemm_k<2, true, false, true, bf16><<<dim3(8 * 64), blk, 0, stream>>>(ffb, W2b, pb2, x2b, zb16, 512, 2048, 8, flag, flag + 1, stats + 32);
    ln_apply_k<true><<<gln, blk, 0, stream>>>(zb16, stats + 32, ln3_w, ln3_b, nullptr, d_out, flag);
}

// Round 18
// 502.200 us; speedup vs baseline: 1.1343x; 1.0134x over previous
//
#include <hip/hip_runtime.h>
#include <hip/hip_bf16.h>

#define B_   8
#define S_   1024
#define D_   512
#define H_   8
#define DK_  64
#define DFF_ 2048

typedef __hip_bfloat16 bf16;
typedef __attribute__((ext_vector_type(8))) short bf16x8;
typedef __attribute__((ext_vector_type(4))) float f32x4;

// flag==1 -> bf16 data; flag==0 -> fp32 data
__device__ __forceinline__ float ldmix(const void* p, size_t i, int f) {
    return f ? __bfloat162float(((const bf16*)p)[i]) : ((const float*)p)[i];
}

// async global->LDS, 16B per lane; lds base wave-uniform (lane*16 implicit)
__device__ __forceinline__ void gl_lds16(const void* g, void* l) {
    __builtin_amdgcn_global_load_lds(
        (const __attribute__((address_space(1))) unsigned int*)g,
        (__attribute__((address_space(3))) unsigned int*)l, 16, 0, 0);
}

#define WAITV(N)  asm volatile("s_waitcnt vmcnt(" #N ")" ::: "memory")
#define WAITLGKM0 asm volatile("s_waitcnt lgkmcnt(0)" ::: "memory")

// ---------------- detect dtype + zero LN stats + constants ----------------
__global__ __launch_bounds__(64) void detect_k(const unsigned short* __restrict__ x,
                                               float* __restrict__ stats,
                                               int* __restrict__ flag)
{
    if (threadIdx.x < 48) stats[threadIdx.x] = 0.f;
    int cnt = 0;
    for (int i = threadIdx.x; i < 4096; i += 64) {
        int e = (x[i] >> 7) & 0xFF;
        if (e >= 0xC0) cnt++;
    }
#pragma unroll
    for (int off = 32; off; off >>= 1) cnt += __shfl_xor(cnt, off);
    if (threadIdx.x == 0) { flag[0] = (cnt > 16) ? 0 : 1; flag[1] = 1; }
}

// ---------------- masks -> additive float ----------------
__global__ __launch_bounds__(256) void maskf_k(const int* __restrict__ trg,
                                               const int* __restrict__ src,
                                               float* __restrict__ trgf,
                                               float* __restrict__ srcf)
{
    int i = blockIdx.x * 256 + threadIdx.x;
    if (i < 8192) trgf[i] = trg[i] ? 0.f : -1.0e10f;
    else          srcf[i - 8192] = src[i - 8192] ? 0.f : -1.0e10f;
}

// ---------------- x,y -> bf16 (8 elems/thread; pure copy when already bf16) ----------------
__global__ __launch_bounds__(256) void convxy_k(const void* __restrict__ x,
                                                const void* __restrict__ y,
                                                bf16* __restrict__ xb, bf16* __restrict__ yb,
                                                const int* __restrict__ flag)
{
    const int f = flag[0];
    const int N8 = 8192 * 512 / 8;   // 524288
    int i = blockIdx.x * 256 + threadIdx.x;
    const void* src; bf16* dst; size_t base;
    if (i < N8) { src = x; dst = xb; base = (size_t)i * 8; }
    else        { src = y; dst = yb; base = (size_t)(i - N8) * 8; }
    if (f) {
        *(uint4*)(dst + base) = *(const uint4*)((const bf16*)src + base);
    } else {
        const float4 a = *(const float4*)((const float*)src + base);
        const float4 b = *(const float4*)((const float*)src + base + 4);
        bf16 o[8] = {__float2bfloat16(a.x), __float2bfloat16(a.y),
                     __float2bfloat16(a.z), __float2bfloat16(a.w),
                     __float2bfloat16(b.x), __float2bfloat16(b.y),
                     __float2bfloat16(b.z), __float2bfloat16(b.w)};
        *(uint4*)(dst + base) = *(uint4*)o;
    }
}

// ---------------- 6 qkv weight repacks: in[h,d,k] -> out[(h*64+k), d] ----------------
__global__ __launch_bounds__(256) void repack6_k(const void* __restrict__ w0, const void* __restrict__ w1,
                                                 const void* __restrict__ w2, const void* __restrict__ w3,
                                                 const void* __restrict__ w4, const void* __restrict__ w5,
                                                 bf16* __restrict__ out, const int* __restrict__ flag)
{
    const int f = flag[0];
    const int widx = blockIdx.x >> 10;
    const int j = ((blockIdx.x & 1023) << 8) + threadIdx.x;
    const void* in = widx == 0 ? w0 : widx == 1 ? w1 : widx == 2 ? w2
                   : widx == 3 ? w3 : widx == 4 ? w4 : w5;
    int n = j >> 9, d = j & 511;
    int h = n >> 6, k = n & 63;
    out[(size_t)widx * 262144 + j] =
        __float2bfloat16(ldmix(in, (size_t)h * (D_ * DK_) + (size_t)d * DK_ + k, f));
}

// ---------------- 4 [N][K] weight converts (8 elems/thread) ----------------
__global__ __launch_bounds__(256) void convw4_k(const void* __restrict__ wo1, const void* __restrict__ wo2,
                                                const void* __restrict__ pw1, const void* __restrict__ pw2,
                                                bf16* __restrict__ out, const int* __restrict__ flag)
{
    const int f = flag[0];
    const size_t i8 = (size_t)(blockIdx.x * 256 + threadIdx.x) * 8;   // < 2621440
    const void* in; size_t off;
    if (i8 < 262144)       { in = wo1; off = 0; }
    else if (i8 < 524288)  { in = wo2; off = 262144; }
    else if (i8 < 1572864) { in = pw1; off = 524288; }
    else                   { in = pw2; off = 1572864; }
    const size_t s = i8 - off;
    if (f) {
        *(uint4*)(out + i8) = *(const uint4*)((const bf16*)in + s);
    } else {
        const float4 a = *(const float4*)((const float*)in + s);
        const float4 b = *(const float4*)((const float*)in + s + 4);
        bf16 o[8] = {__float2bfloat16(a.x), __float2bfloat16(a.y),
                     __float2bfloat16(a.z), __float2bfloat16(a.w),
                     __float2bfloat16(b.x), __float2bfloat16(b.y),
                     __float2bfloat16(b.z), __float2bfloat16(b.w)};
        *(uint4*)(out + i8) = *(uint4*)o;
    }
}

// ==================== MFMA GEMM core (templated BN = NB*32) ====================
// BM=128, BK=32; 4 waves 2x2; wave tile 64 x (NB*16). global_load_lds 16B staging,
// XOR-swizzled LDS, 0 bank conflicts. T3+T4 pipeline: PF=2/1, raw s_barrier +
// counted vmcnt (never 0 mid-loop). UNCHANGED from the measured 508.9us kernel.
// R17 post-mortem: halving write BYTES left dur unchanged -> GEMM is REQUEST-
// throughput-bound, and 73% of a block's requests were the scalar epilogue
// (16x4B res loads + 16x2B stores per thread). R18 change: epilogue-only
// vectorization (LDS transpose -> 16B res loads + 16B stores), 8x fewer requests.
template <int NB>
__device__ __forceinline__ void gemm_core(const bf16* __restrict__ A, const bf16* __restrict__ Wt,
                                          int K, int m0, int n0, bf16* As, bf16* Bs,
                                          f32x4 (&acc)[4][NB])
{
    constexpr int PF   = (NB == 2) ? 2 : 1;   // prefetch depth
    constexpr int NBUF = PF + 1;              // LDS buffers
    const int tid = threadIdx.x;
    const int lane = tid & 63, w = tid >> 6;
    const int wr = w >> 1, wc = w & 1;
    const int l16 = lane & 15, quad = lane >> 4;
    const int r0 = tid >> 2;
    const int g0 = (tid & 3) ^ ((r0 >> 1) & 3);
    const bf16* pa0 = A + (size_t)(m0 + r0) * K + g0 * 8;
    const bf16* pa1 = pa0 + (size_t)64 * K;
    const bf16* pb0 = Wt + (size_t)(n0 + r0) * K + g0 * 8;
    const bf16* pb1 = pb0 + (size_t)64 * K;

    int aoff[4], boff[NB];
#pragma unroll
    for (int i = 0; i < 4; ++i) {
        const int ra = wr * 64 + i * 16 + l16;
        aoff[i] = ra * 32 + (quad ^ ((ra >> 1) & 3)) * 8;
    }
#pragma unroll
    for (int j = 0; j < NB; ++j) {
        const int rb = wc * (NB * 16) + j * 16 + l16;
        boff[j] = rb * 32 + (quad ^ ((rb >> 1) & 3)) * 8;
    }

    // per-wave loads per stage: 3 (NB==2) or 4 (NB==4)
    auto stage = [&](int bi, int k0) {
        bf16* a = As + bi * 4096;
        bf16* b = Bs + bi * (NB * 1024);
        gl_lds16(pa0 + k0, a + w * 512);
        gl_lds16(pa1 + k0, a + 2048 + w * 512);
        gl_lds16(pb0 + k0, b + w * 512);
        if constexpr (NB == 4) gl_lds16(pb1 + k0, b + 2048 + w * 512);
    };

    const int NT = K >> 5;
    stage(0, 0);
    if constexpr (PF == 2) stage(1, 32);
    int cur = 0, nxt = PF;

    for (int t = 0; t < NT; ++t) {
        if (t + PF < NT) {
            stage(nxt, (t + PF) << 5);
            if constexpr (NB == 4) WAITV(4); else WAITV(6);
        } else if (t + 1 < NT) {
            WAITV(3);
        } else {
            WAITV(0);
        }
        __builtin_amdgcn_s_barrier();
        __builtin_amdgcn_sched_barrier(0);

        const bf16* Ab = As + cur * 4096;
        const bf16* Bb = Bs + cur * (NB * 1024);
        bf16x8 af[4], bg[NB];
#pragma unroll
        for (int i = 0; i < 4; ++i) af[i] = *(const bf16x8*)&Ab[aoff[i]];
#pragma unroll
        for (int j = 0; j < NB; ++j) bg[j] = *(const bf16x8*)&Bb[boff[j]];
#pragma unroll
        for (int i = 0; i < 4; ++i)
#pragma unroll
            for (int j = 0; j < NB; ++j)
                acc[i][j] = __builtin_amdgcn_mfma_f32_16x16x32_bf16(af[i], bg[j], acc[i][j], 0, 0, 0);

        WAITLGKM0;
        __builtin_amdgcn_sched_barrier(0);
        __builtin_amdgcn_s_barrier();
        cur = (cur + 1 == NBUF) ? 0 : cur + 1;
        nxt = (nxt + 1 == NBUF) ? 0 : nxt + 1;
    }
}

// standard GEMM: C[M,N] = A @ Wt^T + bias (+relu) (+res) (+LN-stats)
// Vectorized epilogue: per 32rowx64col round, stage acc in LDS (fp32, +4 pad),
// read back 8 consecutive cols/thread -> one 16B store (+16B res load).
template <int NB, bool HAS_RES, bool RELU, bool STATS, typename OutT>
__global__ __launch_bounds__(256)
void mgemm_k(const bf16* __restrict__ A, const bf16* __restrict__ Wt,
             const void* __restrict__ bias, const void* __restrict__ res,
             OutT* __restrict__ C, int N, int K, int Gx,
             const int* __restrict__ bflag, const int* __restrict__ rflag,
             float* __restrict__ stats)
{
    constexpr int NBUF = (NB == 2) ? 3 : 2;
    __shared__ bf16 As[NBUF * 4096];
    __shared__ bf16 Bs[NBUF * NB * 1024];
    const int lin = blockIdx.x;
    const int mt = (lin & 7) * 8 + (lin >> 3) / Gx;
    const int nt = (lin >> 3) % Gx;
    const int m0 = mt * 128, n0 = nt * (NB * 32);

    f32x4 acc[4][NB];
#pragma unroll
    for (int i = 0; i < 4; ++i)
#pragma unroll
        for (int j = 0; j < NB; ++j) acc[i][j] = (f32x4){0.f, 0.f, 0.f, 0.f};

    gemm_core<NB>(A, Wt, K, m0, n0, As, Bs, acc);

    const int tid = threadIdx.x;
    const int lane = tid & 63, w = tid >> 6;
    const int wr = w >> 1, wc = w & 1;
    const int l16 = lane & 15, quad = lane >> 4;
    const int bf = bflag[0];
    int rf = 0;
    if constexpr (HAS_RES) rf = rflag[0];

    constexpr int STR = 68;            // 64 cols + 4 pad (floats), conflict-free
    float* stg = (float*)As;           // 32*68*4 = 8704 B <= As for NB=2/4
    constexpr int NROUND = (NB == 2) ? 1 : 2;
    float s = 0.f, s2 = 0.f;
    const int lrow = tid >> 3;         // 0..31
    const int c0 = (tid & 7) * 8;      // 0..56

#pragma unroll
    for (int i = 0; i < 4; ++i) {
#pragma unroll
        for (int jh = 0; jh < NROUND; ++jh) {
            __syncthreads();
            // ---- write phase: stage this round's 32x64 fp32 sub-tile ----
            if constexpr (NB == 2) {
#pragma unroll
                for (int j = 0; j < 2; ++j)
#pragma unroll
                    for (int r = 0; r < 4; ++r)
                        stg[(wr * 16 + quad * 4 + r) * STR + wc * 32 + j * 16 + l16] = acc[i][j][r];
            } else {
                if (wc == jh) {
#pragma unroll
                    for (int j = 0; j < 4; ++j)
#pragma unroll
                        for (int r = 0; r < 4; ++r)
                            stg[(wr * 16 + quad * 4 + r) * STR + j * 16 + l16] = acc[i][j][r];
                }
            }
            __syncthreads();
            // ---- read/store phase: 8 consecutive cols per thread ----
            float v[8];
            *(float4*)&v[0] = *(const float4*)&stg[lrow * STR + c0];
            *(float4*)&v[4] = *(const float4*)&stg[lrow * STR + c0 + 4];
            const int grow = m0 + (lrow >> 4) * 64 + i * 16 + (lrow & 15);
            const int gcol = n0 + jh * 64 + c0;
            if constexpr (HAS_RES) {
                if (rf) {
                    union { uint4 u; unsigned short us[8]; } ri;
                    ri.u = *(const uint4*)((const bf16*)res + (size_t)grow * N + gcol);
#pragma unroll
                    for (int k = 0; k < 8; ++k) {
                        bf16 t; __builtin_memcpy(&t, &ri.us[k], 2);
                        v[k] += __bfloat162float(t);
                    }
                } else {
                    const float4 ra = *(const float4*)((const float*)res + (size_t)grow * N + gcol);
                    const float4 rb = *(const float4*)((const float*)res + (size_t)grow * N + gcol + 4);
                    v[0] += ra.x; v[1] += ra.y; v[2] += ra.z; v[3] += ra.w;
                    v[4] += rb.x; v[5] += rb.y; v[6] += rb.z; v[7] += rb.w;
                }
            }
#pragma unroll
            for (int k = 0; k < 8; ++k) {
                float c = v[k] + ldmix(bias, gcol + k, bf);
                if constexpr (RELU) c = fmaxf(c, 0.f);
                if constexpr (STATS) { s += c; s2 += c * c; }
                v[k] = c;
            }
            union { uint4 u; unsigned short us[8]; } ov;
#pragma unroll
            for (int k = 0; k < 8; ++k) {
                bf16 t = __float2bfloat16(v[k]);
                __builtin_memcpy(&ov.us[k], &t, 2);
            }
            *(uint4*)((bf16*)C + (size_t)grow * N + gcol) = ov.u;
        }
    }

    if constexpr (STATS) {
#pragma unroll
        for (int off = 32; off; off >>= 1) { s += __shfl_xor(s, off); s2 += __shfl_xor(s2, off); }
        __syncthreads();                     // all waves done with stg
        float* red = (float*)As;
        if (lane == 0) { red[w * 2] = s; red[w * 2 + 1] = s2; }
        __syncthreads();
        if (tid == 0) {
            const int b = m0 >> 10;
            atomicAdd(&stats[b * 2],     red[0] + red[2] + red[4] + red[6]);
            atomicAdd(&stats[b * 2 + 1], red[1] + red[3] + red[5] + red[7]);
        }
    }
}

// fused projection GEMM: routes Q (x0.125) / K / V(transposed) by 512-col region.
// q/k: LDS-transpose vectorized 16B stores; V: native 4-consecutive-key uint2 (8B).
template <int NB, int RSHIFT>
__global__ __launch_bounds__(256)
void mgemm_qkv_k(const bf16* __restrict__ A, const bf16* __restrict__ Wbase,
                 const void* __restrict__ bq, const void* __restrict__ bk, const void* __restrict__ bv,
                 bf16* __restrict__ qout, bf16* __restrict__ kout, bf16* __restrict__ vtout,
                 int Gx, int roff, const int* __restrict__ bflag)
{
    constexpr int NBUF = (NB == 2) ? 3 : 2;
    __shared__ bf16 As[NBUF * 4096];
    __shared__ bf16 Bs[NBUF * NB * 1024];
    const int lin = blockIdx.x;
    const int mt = (lin & 7) * 8 + (lin >> 3) / Gx;
    const int nt = (lin >> 3) % Gx;
    const int m0 = mt * 128, n0 = nt * (NB * 32);

    f32x4 acc[4][NB];
#pragma unroll
    for (int i = 0; i < 4; ++i)
#pragma unroll
        for (int j = 0; j < NB; ++j) acc[i][j] = (f32x4){0.f, 0.f, 0.f, 0.f};

    gemm_core<NB>(A, Wbase, 512, m0, n0, As, Bs, acc);

    const int tid = threadIdx.x;
    const int lane = tid & 63, w = tid >> 6;
    const int wr = w >> 1, wc = w & 1;
    const int l16 = lane & 15, quad = lane >> 4;
    const int bf = bflag[0];
    const int region = roff + (nt >> RSHIFT);   // block-uniform

    if (region == 2) {
        // V-transpose: 4 consecutive keys (rows) per fragment column -> 8B stores
#pragma unroll
        for (int i = 0; i < 4; ++i) {
            const int row = m0 + wr * 64 + i * 16 + quad * 4;
#pragma unroll
            for (int j = 0; j < NB; ++j) {
                const int col = n0 + wc * (NB * 16) + j * 16 + l16;
                const int colr = col & 511;
                const float bvv = ldmix(bv, colr, bf);
                union { uint2 u; unsigned short us[4]; } ov;
#pragma unroll
                for (int r = 0; r < 4; ++r) {
                    bf16 t = __float2bfloat16(acc[i][j][r] + bvv);
                    __builtin_memcpy(&ov.us[r], &t, 2);
                }
                const int b = row >> 10, key = row & 1023;
                *(uint2*)&vtout[((size_t)(b * 512 + colr) << 10) | key] = ov.u;
            }
        }
    } else {
        bf16* outp = region == 0 ? qout : kout;
        const void* bptr = region == 0 ? bq : bk;
        const float scale = region == 0 ? 0.125f : 1.0f;
        constexpr int STR = 68;
        float* stg = (float*)As;
        constexpr int NROUND = (NB == 2) ? 1 : 2;
        const int lrow = tid >> 3;
        const int c0 = (tid & 7) * 8;
#pragma unroll
        for (int i = 0; i < 4; ++i) {
#pragma unroll
            for (int jh = 0; jh < NROUND; ++jh) {
                __syncthreads();
                if constexpr (NB == 2) {
#pragma unroll
                    for (int j = 0; j < 2; ++j)
#pragma unroll
                        for (int r = 0; r < 4; ++r)
                            stg[(wr * 16 + quad * 4 + r) * STR + wc * 32 + j * 16 + l16] = acc[i][j][r];
                } else {
                    if (wc == jh) {
#pragma unroll
                        for (int j = 0; j < 4; ++j)
#pragma unroll
                            for (int r = 0; r < 4; ++r)
                                stg[(wr * 16 + quad * 4 + r) * STR + j * 16 + l16] = acc[i][j][r];
                    }
                }
                __syncthreads();
                float v[8];
                *(float4*)&v[0] = *(const float4*)&stg[lrow * STR + c0];
                *(float4*)&v[4] = *(const float4*)&stg[lrow * STR + c0 + 4];
                const int grow = m0 + (lrow >> 4) * 64 + i * 16 + (lrow & 15);
                const int gcol = n0 + jh * 64 + c0;
                const int colr0 = gcol & 511;
                union { uint4 u; unsigned short us[8]; } ov;
#pragma unroll
                for (int k = 0; k < 8; ++k) {
                    const float c = (v[k] + ldmix(bptr, colr0 + k, bf)) * scale;
                    bf16 t = __float2bfloat16(c);
                    __builtin_memcpy(&ov.us[k], &t, 2);
                }
                *(uint4*)&outp[(size_t)grow * 512 + colr0] = ov.u;
            }
        }
    }
}

// ---------------- MFMA flash attention, fixed-max softmax ----------------
// 1-D grid 1024: xcd=lin&7 owns 8 heads; all 16 q-tiles of a head on one XCD.
__global__ __launch_bounds__(256)
void mfattn_k(const bf16* __restrict__ Q, const bf16* __restrict__ Kb,
              const bf16* __restrict__ Vt, const float* __restrict__ maskf,
              bf16* __restrict__ O)
{
    const int lin = blockIdx.x;
    const int j = lin >> 3, xcd = lin & 7;
    const int head = xcd * 8 + (j >> 4);
    const int qt = j & 15;
    const int b = head >> 3, h = head & 7, s0 = qt * 64;
    const int tid = threadIdx.x;
    const int lane = tid & 63, w = tid >> 6;
    const int l16 = lane & 15, quad = lane >> 4;
    const int bS = b * S_, hc = h * DK_;
    const size_t vtb = (size_t)(b * H_ + h) * (DK_ * S_);

    __shared__ bf16 QPs[64 * 72];
    __shared__ bf16 Ks[64 * 72];
    __shared__ bf16 Vs[64 * 72];

    const int str = tid >> 3;
    const int stc = (tid & 7) * 8;

    *(uint4*)&QPs[str * 72 + stc]        = *(const uint4*)&Q[(size_t)(bS + s0 + str) * D_ + hc + stc];
    *(uint4*)&QPs[(str + 32) * 72 + stc] = *(const uint4*)&Q[(size_t)(bS + s0 + str + 32) * D_ + hc + stc];
    __syncthreads();

    const bf16x8 aq0 = *(const bf16x8*)&QPs[(w * 16 + l16) * 72 + quad * 8];
    const bf16x8 aq1 = *(const bf16x8*)&QPs[(w * 16 + l16) * 72 + quad * 8 + 32];

    f32x4 acc_o[4];
#pragma unroll
    for (int nb = 0; nb < 4; ++nb) acc_o[nb] = (f32x4){0.f, 0.f, 0.f, 0.f};
    float lrow[4] = {0.f, 0.f, 0.f, 0.f};

    for (int t0 = 0; t0 < S_; t0 += 64) {
        __syncthreads();
        *(uint4*)&Ks[str * 72 + stc]        = *(const uint4*)&Kb[(size_t)(bS + t0 + str) * D_ + hc + stc];
        *(uint4*)&Ks[(str + 32) * 72 + stc] = *(const uint4*)&Kb[(size_t)(bS + t0 + str + 32) * D_ + hc + stc];
        *(uint4*)&Vs[str * 72 + stc]        = *(const uint4*)&Vt[vtb + (size_t)str * S_ + t0 + stc];
        *(uint4*)&Vs[(str + 32) * 72 + stc] = *(const uint4*)&Vt[vtb + (size_t)(str + 32) * S_ + t0 + stc];
        __syncthreads();

        f32x4 sacc[4];
#pragma unroll
        for (int nb = 0; nb < 4; ++nb) sacc[nb] = (f32x4){0.f, 0.f, 0.f, 0.f};
#pragma unroll
        for (int nb = 0; nb < 4; ++nb) {
            const bf16x8 b0 = *(const bf16x8*)&Ks[(nb * 16 + l16) * 72 + quad * 8];
            const bf16x8 b1 = *(const bf16x8*)&Ks[(nb * 16 + l16) * 72 + quad * 8 + 32];
            sacc[nb] = __builtin_amdgcn_mfma_f32_16x16x32_bf16(aq0, b0, sacc[nb], 0, 0, 0);
            sacc[nb] = __builtin_amdgcn_mfma_f32_16x16x32_bf16(aq1, b1, sacc[nb], 0, 0, 0);
        }

#pragma unroll
        for (int nb = 0; nb < 4; ++nb) {
            const float mv = maskf[bS + t0 + nb * 16 + l16];
#pragma unroll
            for (int r = 0; r < 4; ++r) {
                const float p = __expf(sacc[nb][r] + mv);
                lrow[r] += p;
                QPs[(w * 16 + quad * 4 + r) * 72 + nb * 16 + l16] = __float2bfloat16(p);
            }
        }

        const bf16x8 ap0 = *(const bf16x8*)&QPs[(w * 16 + l16) * 72 + quad * 8];
        const bf16x8 ap1 = *(const bf16x8*)&QPs[(w * 16 + l16) * 72 + quad * 8 + 32];
#pragma unroll
        for (int nb = 0; nb < 4; ++nb) {
            const bf16x8 v0 = *(const bf16x8*)&Vs[(nb * 16 + l16) * 72 + quad * 8];
            const bf16x8 v1 = *(const bf16x8*)&Vs[(nb * 16 + l16) * 72 + quad * 8 + 32];
            acc_o[nb] = __builtin_amdgcn_mfma_f32_16x16x32_bf16(ap0, v0, acc_o[nb], 0, 0, 0);
            acc_o[nb] = __builtin_amdgcn_mfma_f32_16x16x32_bf16(ap1, v1, acc_o[nb], 0, 0, 0);
        }
    }

#pragma unroll
    for (int r = 0; r < 4; ++r) {
        float ls = lrow[r];
#pragma unroll
        for (int off = 8; off; off >>= 1) ls += __shfl_xor(ls, off);
        const float invl = 1.0f / ls;
        const size_t row = (size_t)(bS + s0 + w * 16 + quad * 4 + r) * D_;
#pragma unroll
        for (int nb = 0; nb < 4; ++nb)
            O[row + hc + nb * 16 + l16] = __float2bfloat16(acc_o[nb][r] * invl);
    }
}

// ---------------- LayerNorm apply (stats from GEMM epilogues; Z stored bf16) ----------------
template <bool FINAL>
__global__ __launch_bounds__(256)
void ln_apply_k(const bf16* __restrict__ Z, const float* __restrict__ stats,
                const void* __restrict__ w, const void* __restrict__ bb,
                bf16* __restrict__ outb, void* __restrict__ out_final,
                const int* __restrict__ flag)
{
    const int f = flag[0];
    const int b = blockIdx.y;
    const int i4 = (blockIdx.x * 256 + threadIdx.x) * 4;
    const float n = (float)(S_ * D_);
    const float m = stats[b * 2] / n;
    const float var = stats[b * 2 + 1] / n - m * m;
    const float inv = rsqrtf(var + 1e-6f);
    const size_t g = (size_t)b * (S_ * D_) + i4;
    union { ushort4 u4; unsigned short u[4]; } zi;
    zi.u4 = *(const ushort4*)&Z[g];
    float v[4];
#pragma unroll
    for (int k = 0; k < 4; ++k) {
        bf16 t;
        __builtin_memcpy(&t, &zi.u[k], 2);
        v[k] = (__bfloat162float(t) - m) * inv * ldmix(w, i4 + k, f) + ldmix(bb, i4 + k, f);
    }
    union { ushort4 u4; unsigned short u[4]; } ov;
#pragma unroll
    for (int k = 0; k < 4; ++k) {
        bf16 t = __float2bfloat16(v[k]);
        __builtin_memcpy(&ov.u[k], &t, 2);
    }
    if constexpr (FINAL) {
        if (f) *(ushort4*)&((bf16*)out_final)[g] = ov.u4;
        else   *(float4*)&((float*)out_final)[g] = make_float4(v[0], v[1], v[2], v[3]);
    } else {
        *(ushort4*)&outb[g] = ov.u4;
    }
}

// ---------------- orchestration ----------------
extern "C" void kernel_launch(void* const* d_in, const int* in_sizes, int n_in,
                              void* d_out, int out_size, void* d_ws, size_t ws_size,
                              hipStream_t stream)
{
    (void)in_sizes; (void)n_in; (void)out_size; (void)ws_size;

    const void* x        = d_in[0];
    const void* y        = d_in[1];
    const int*  src_mask = (const int*) d_in[2];
    const int*  trg_mask = (const int*) d_in[3];
    const void* m1_wq = d_in[4];
    const void* m1_bq = d_in[5];
    const void* m1_wk = d_in[6];
    const void* m1_bk = d_in[7];
    const void* m1_wv = d_in[8];
    const void* m1_bv = d_in[9];
    const void* m1_wo = d_in[10];
    const void* m1_bo = d_in[11];
    const void* m2_wq = d_in[12];
    const void* m2_bq = d_in[13];
    const void* m2_wk = d_in[14];
    const void* m2_bk = d_in[15];
    const void* m2_wv = d_in[16];
    const void* m2_bv = d_in[17];
    const void* m2_wo = d_in[18];
    const void* m2_bo = d_in[19];
    const void* pw1   = d_in[20];
    const void* pb1   = d_in[21];
    const void* pw2   = d_in[22];
    const void* pb2   = d_in[23];
    const void* ln1_w = d_in[24];
    const void* ln1_b = d_in[25];
    const void* ln2_w = d_in[26];
    const void* ln2_b = d_in[27];
    const void* ln3_w = d_in[28];
    const void* ln3_b = d_in[29];

    const size_t NACT = (size_t)8192 * 512;

    float* zb    = (float*)d_ws;               // region sized NACT floats; stores bf16
    bf16*  zb16  = (bf16*)zb;
    float* stats = zb + NACT;
    int*   flag  = (int*)(stats + 48);
    float* trgf  = stats + 64;
    float* srcf  = trgf + 8192;
    bf16* xb16 = (bf16*)(srcf + 8192);
    bf16* yb16 = xb16 + NACT;
    bf16* qb   = yb16 + NACT;
    bf16* kb   = qb   + NACT;
    bf16* vbT  = kb   + NACT;
    bf16* aob  = vbT  + NACT;
    bf16* x1b  = aob  + NACT;
    bf16* x2b  = x1b  + NACT;
    bf16* ffb  = x2b  + NACT;
    bf16* Wq1r = ffb  + (size_t)8192 * 2048;
    bf16* Wq2r = Wq1r + 3 * 262144;
    bf16* Wo1b = Wq1r + 6 * 262144;
    bf16* Wo2b = Wo1b + 262144;
    bf16* W1b  = Wo2b + 262144;
    bf16* W2b  = W1b  + 1048576;

    detect_k<<<1, 64, 0, stream>>>((const unsigned short*)x, stats, flag);
    maskf_k<<<64, 256, 0, stream>>>(trg_mask, src_mask, trgf, srcf);
    convxy_k<<<4096, 256, 0, stream>>>(x, y, xb16, yb16, flag);
    repack6_k<<<6144, 256, 0, stream>>>(m1_wq, m1_wk, m1_wv, m2_wq, m2_wk, m2_wv, Wq1r, flag);
    convw4_k<<<1280, 256, 0, stream>>>(m1_wo, m2_wo, pw1, pw2, Wo1b, flag);

    const dim3 blk(256);
    const dim3 gln(512, B_);

    // ---- self-attention ----
    mgemm_qkv_k<4, 2><<<dim3(12 * 64), blk, 0, stream>>>(xb16, Wq1r, m1_bq, m1_bk, m1_bv, qb, kb, vbT, 12, 0, flag);
    mfattn_k<<<dim3(1024), blk, 0, stream>>>(qb, kb, vbT, trgf, aob);
    mgemm_k<2, true, false, true, bf16><<<dim3(8 * 64), blk, 0, stream>>>(aob, Wo1b, m1_bo, x, zb16, 512, 512, 8, flag, flag, stats);
    ln_apply_k<false><<<gln, blk, 0, stream>>>(zb16, stats, ln1_w, ln1_b, x1b, nullptr, flag);

    // ---- cross-attention ----
    mgemm_qkv_k<2, 3><<<dim3(8 * 64), blk, 0, stream>>>(x1b, Wq2r, m2_bq, m2_bk, m2_bv, qb, kb, vbT, 8, 0, flag);
    mgemm_qkv_k<4, 2><<<dim3(8 * 64), blk, 0, stream>>>(yb16, Wq2r + 262144, m2_bq, m2_bk, m2_bv, qb, kb, vbT, 8, 1, flag);
    mfattn_k<<<dim3(1024), blk, 0, stream>>>(qb, kb, vbT, srcf, aob);
    mgemm_k<2, true, false, true, bf16><<<dim3(8 * 64), blk, 0, stream>>>(aob, Wo2b, m2_bo, x1b, zb16, 512, 512, 8, flag, flag + 1, stats + 16);
    ln_apply_k<false><<<gln, blk, 0, stream>>>(zb16, stats + 16, ln2_w, ln2_b, x2b, nullptr, flag);

    // ---- FFN ----
    mgemm_k<4, false, true, false, bf16><<<dim3(16 * 64), blk, 0, stream>>>(x2b, W1b, pb1, nullptr, ffb, 2048, 512, 16, flag, flag, nullptr);
    mgemm_k<2, true, false, true, bf16><<<dim3(8 * 64), blk, 0, stream>>>(ffb, W2b, pb2, x2b, zb16, 512, 2048, 8, flag, flag + 1, stats + 32);
    ln_apply_k<true><<<gln, blk, 0, stream>>>(zb16, stats + 32, ln3_w, ln3_b, nullptr, d_out, flag);
}